// Round 8
// baseline (310.407 us; speedup 1.0000x reference)
//
#include <hip/hip_runtime.h>
#include <hip/hip_cooperative_groups.h>
#include <math.h>

namespace cg = cooperative_groups;

#define BB 2
#define NN 1024
#define CC 256
#define NQ 100
#define HALF 128

typedef __attribute__((ext_vector_type(8))) short bf16x8;
typedef __attribute__((ext_vector_type(4))) float f32x4;

__device__ __forceinline__ float exp2_fast(float v) {
#if __has_builtin(__builtin_amdgcn_exp2f)
    return __builtin_amdgcn_exp2f(v);
#else
    return __expf(0.69314718056f * v);
#endif
}

// gelu tanh-form: x * sigmoid(2*c1*(x + c2*x^3)); |err vs erf-gelu| <= ~3e-4.
__device__ __forceinline__ float gelu_fast(float x) {
    float x2 = x * x;
    float v = x * fmaf(0.10293942f, x2, 2.30211418f);
    float e = exp2_fast(v);
    float r = __builtin_amdgcn_rcpf(1.0f + e);
    return fmaf(-x, r, x);
}

// fp32 -> bf16 RNE
__device__ __forceinline__ short f2bf(float f) {
    union { float f; unsigned u; } v; v.f = f;
    return (short)((v.u + 0x7FFFu + ((v.u >> 16) & 1u)) >> 16);
}

// ---- ONE cooperative kernel, three phases separated by grid.sync(). ----
// Phase 1 (tiles 0..511): LN -> W_in GEMM -> gelu -> gpart/ppart; h_local@W1
//   -> At (MFMA-A-frag tiled At[((b*64+row/16)*32+k/8)*128+(row%16)*8+k%8]).
//   (tiles 512..543): W2 -> bf16 MFMA-B-frag tiled W2T.
// Phase 2 (tiles 0..199): Qc[b,i] = q@W1[256:512] + glob@W1[128:256] + b1.
// Phase 3 (tiles 0..3199): z1 = gelu(At+Qc) in-register -> MFMA vs frag-tiled
//   LDS W2 (dbuf, conflict-free) -> gelu -> W3 -> log_softmax -> out.
__global__ __launch_bounds__(256, 4) void mega(
        const float* __restrict__ x, const float* __restrict__ ln_g,
        const float* __restrict__ ln_b, const float* __restrict__ W_in,
        const float* __restrict__ b_in, const float* __restrict__ policy,
        const float* __restrict__ query, const float* __restrict__ W1,
        const float* __restrict__ W2, const float* __restrict__ b1,
        const float* __restrict__ b2, const float* __restrict__ W3,
        const float* __restrict__ b3, float* __restrict__ At,
        float* __restrict__ Qc, float* __restrict__ gpart,
        float* __restrict__ ppart, short* __restrict__ W2T,
        float* __restrict__ out) {
    cg::grid_group gg = cg::this_grid();
    __shared__ __align__(16) char smem[16384];
    int t = threadIdx.x;
    int nb = gridDim.x;

    // ================= phase 1 =================
    {
        float* xst = (float*)smem;             // [256][4]
        float* hst = (float*)(smem + 4096);    // [128][4]
        for (int blk = blockIdx.x; blk < 544; blk += nb) {
            if (blk >= 512) {
                int u = (blk - 512) * 256 + t;
                int n = u & 127;               // lane-varying -> coalesced
                int kq = u >> 7;
                short4 v;
                v.x = f2bf(W2[(kq * 4 + 0) * HALF + n]);
                v.y = f2bf(W2[(kq * 4 + 1) * HALF + n]);
                v.z = f2bf(W2[(kq * 4 + 2) * HALF + n]);
                v.w = f2bf(W2[(kq * 4 + 3) * HALF + n]);
                *(short4*)(W2T + (size_t)((n >> 4) * 32 + (kq >> 1)) * 128
                           + (n & 15) * 8 + (kq & 1) * 4) = v;
            } else {
                int wave = t >> 6, lane = t & 63;
                int row0 = blk * 4;
                const float* xr = x + (size_t)(row0 + wave) * CC;
                float v0 = xr[lane], v1 = xr[lane + 64];
                float v2 = xr[lane + 128], v3 = xr[lane + 192];
                float s = v0 + v1 + v2 + v3;
                for (int off = 32; off; off >>= 1) s += __shfl_down(s, off);
                s = __shfl(s, 0);
                float mu = s * (1.0f / CC);
                float d0 = v0 - mu, d1 = v1 - mu, d2 = v2 - mu, d3 = v3 - mu;
                float vs = d0 * d0 + d1 * d1 + d2 * d2 + d3 * d3;
                for (int off = 32; off; off >>= 1) vs += __shfl_down(vs, off);
                vs = __shfl(vs, 0);
                float rstd = rsqrtf(vs * (1.0f / CC) + 1e-5f);
                xst[(lane)*4 + wave]       = d0 * rstd * ln_g[lane]       + ln_b[lane];
                xst[(lane + 64)*4 + wave]  = d1 * rstd * ln_g[lane + 64]  + ln_b[lane + 64];
                xst[(lane + 128)*4 + wave] = d2 * rstd * ln_g[lane + 128] + ln_b[lane + 128];
                xst[(lane + 192)*4 + wave] = d3 * rstd * ln_g[lane + 192] + ln_b[lane + 192];
                __syncthreads();
                // GEMM1: h = gelu(LN(x)@W_in + b_in)
                float a0 = b_in[t], a1 = a0, a2 = a0, a3 = a0;
                #pragma unroll 8
                for (int k = 0; k < CC; ++k) {
                    float4 xv = *(const float4*)&xst[k * 4];  // broadcast
                    float wv = W_in[k * CC + t];
                    a0 = fmaf(xv.x, wv, a0); a1 = fmaf(xv.y, wv, a1);
                    a2 = fmaf(xv.z, wv, a2); a3 = fmaf(xv.w, wv, a3);
                }
                float h0 = gelu_fast(a0), h1 = gelu_fast(a1);
                float h2 = gelu_fast(a2), h3 = gelu_fast(a3);
                float p0 = policy[row0], p1 = policy[row0 + 1];
                float p2 = policy[row0 + 2], p3 = policy[row0 + 3];
                if (t < HALF) {
                    hst[t * 4 + 0] = h0; hst[t * 4 + 1] = h1;
                    hst[t * 4 + 2] = h2; hst[t * 4 + 3] = h3;
                } else {
                    gpart[(size_t)blk * HALF + (t - HALF)] =
                        h0 * p0 + h1 * p1 + h2 * p2 + h3 * p3;
                }
                if (t == 0) ppart[blk] = p0 + p1 + p2 + p3;
                __syncthreads();
                // GEMM2: At = h_local @ W1[0:128]
                float c0 = 0, c1 = 0, c2 = 0, c3 = 0;
                #pragma unroll 8
                for (int k = 0; k < HALF; ++k) {
                    float4 hv = *(const float4*)&hst[k * 4];  // broadcast
                    float wv = W1[k * CC + t];
                    c0 = fmaf(hv.x, wv, c0); c1 = fmaf(hv.y, wv, c1);
                    c2 = fmaf(hv.z, wv, c2); c3 = fmaf(hv.w, wv, c3);
                }
                int b = row0 >> 10;
                int lr = row0 & (NN - 1);
                size_t tb = ((size_t)(b * 64 + (lr >> 4)) * 32 + (t >> 3)) * 128 + (t & 7);
                int r16 = lr & 15;
                At[tb + (r16 + 0) * 8] = c0;
                At[tb + (r16 + 1) * 8] = c1;
                At[tb + (r16 + 2) * 8] = c2;
                At[tb + (r16 + 3) * 8] = c3;
            }
            __syncthreads();
        }
    }
    gg.sync();

    // ================= phase 2 =================
    {
        float* gl2 = (float*)smem;             // [2][128]
        float* gls = (float*)(smem + 1024);    // [128]
        float* qs  = (float*)(smem + 1536);    // [256]
        float* pss = (float*)(smem + 2560);    // [1]
        for (int blk = blockIdx.x; blk < BB * NQ; blk += nb) {
            int b = blk / NQ, i = blk % NQ;
            int c = t & 127, hh = t >> 7;
            {
                const float* gp = gpart + ((size_t)b * 256 + hh * 128) * HALF + c;
                float s = 0.f;
                #pragma unroll 16
                for (int ch = 0; ch < 128; ++ch) s += gp[(size_t)ch * HALF];
                gl2[hh * HALF + c] = s;
            }
            if (t < 64) {
                const float* pp = ppart + b * 256;
                float ps = pp[t] + pp[t + 64] + pp[t + 128] + pp[t + 192];
                for (int off = 32; off; off >>= 1) ps += __shfl_down(ps, off);
                if (t == 0) pss[0] = ps;
            }
            qs[t] = query[(size_t)(i * BB + b) * CC + t];
            __syncthreads();
            if (t < HALF) gls[t] = (gl2[t] + gl2[HALF + t]) / pss[0];
            __syncthreads();
            float g = b1[t];
            #pragma unroll 8
            for (int k = 0; k < HALF; ++k)
                g = fmaf(gls[k], W1[(HALF + k) * CC + t], g);
            #pragma unroll 8
            for (int k = 0; k < CC; ++k)
                g = fmaf(qs[k], W1[(2 * HALF + k) * CC + t], g);
            Qc[(size_t)blk * CC + t] = g;
            __syncthreads();
        }
    }
    gg.sync();

    // ================= phase 3 =================
    {
        short* w2s = (short*)smem;   // [2][4096]
        int lane = t & 63, w = t >> 6;
        int col16 = lane & 15, quad = lane >> 4;
        const short* Wg = W2T + (size_t)((t >> 6) * 32 + ((t >> 4) & 3)) * 128
                          + (t & 15) * 8;
        float b30 = b3[0], b31 = b3[1];
        for (int blk = blockIdx.x; blk < BB * NQ * (NN / 64); blk += nb) {
            int jt = blk & 15;
            int iq = (blk >> 4) % NQ;
            int b  = blk / (16 * NQ);
            const float* Abase = At + ((size_t)(b * 64 + jt * 4 + w) * 32) * 128
                                 + col16 * 8;
            const float* Qrow = Qc + (size_t)(b * NQ + iq) * CC;

            f32x4 acc[8];
            #pragma unroll
            for (int ni = 0; ni < 8; ++ni) acc[ni] = (f32x4){0.f, 0.f, 0.f, 0.f};

            // prologue: chunk 0 -> buf0; preload chunk 1 + A/Q(0) -> regs
            bf16x8 nx0 = *(const bf16x8*)(Wg);
            bf16x8 nx1 = *(const bf16x8*)(Wg + 16384);
            float4 a0 = *(const float4*)(Abase + quad * 128);
            float4 a1 = *(const float4*)(Abase + quad * 128 + 4);
            float4 q0 = *(const float4*)(Qrow + quad * 8);
            float4 q1 = *(const float4*)(Qrow + quad * 8 + 4);
            *(bf16x8*)&w2s[t * 8] = nx0;
            *(bf16x8*)&w2s[2048 + t * 8] = nx1;
            nx0 = *(const bf16x8*)(Wg + 512);
            nx1 = *(const bf16x8*)(Wg + 16384 + 512);
            __syncthreads();

            #pragma unroll
            for (int kt = 0; kt < 8; ++kt) {
                int buf = kt & 1;
                if (kt < 7) {
                    *(bf16x8*)&w2s[(1 - buf) * 4096 + t * 8] = nx0;
                    *(bf16x8*)&w2s[(1 - buf) * 4096 + 2048 + t * 8] = nx1;
                }
                if (kt < 6) {
                    nx0 = *(const bf16x8*)(Wg + (kt + 2) * 512);
                    nx1 = *(const bf16x8*)(Wg + 16384 + (kt + 2) * 512);
                }
                union { bf16x8 v; short s[8]; } fr;
                fr.s[0] = f2bf(gelu_fast(a0.x + q0.x));
                fr.s[1] = f2bf(gelu_fast(a0.y + q0.y));
                fr.s[2] = f2bf(gelu_fast(a0.z + q0.z));
                fr.s[3] = f2bf(gelu_fast(a0.w + q0.w));
                fr.s[4] = f2bf(gelu_fast(a1.x + q1.x));
                fr.s[5] = f2bf(gelu_fast(a1.y + q1.y));
                fr.s[6] = f2bf(gelu_fast(a1.z + q1.z));
                fr.s[7] = f2bf(gelu_fast(a1.w + q1.w));
                if (kt < 7) {
                    const float* Ap = Abase + (size_t)((kt + 1) * 4 + quad) * 128;
                    a0 = *(const float4*)(Ap);
                    a1 = *(const float4*)(Ap + 4);
                    q0 = *(const float4*)(Qrow + (kt + 1) * 32 + quad * 8);
                    q1 = *(const float4*)(Qrow + (kt + 1) * 32 + quad * 8 + 4);
                }
                #pragma unroll
                for (int ni = 0; ni < 8; ++ni) {
                    bf16x8 bv = *(const bf16x8*)&w2s[buf * 4096 + (ni * 64 + lane) * 8];
                    acc[ni] = __builtin_amdgcn_mfma_f32_16x16x32_bf16(fr.v, bv,
                                                                      acc[ni], 0, 0, 0);
                }
                if (kt < 7) __syncthreads();
            }

            // epilogue
            float p0[4] = {0, 0, 0, 0}, p1[4] = {0, 0, 0, 0};
            #pragma unroll
            for (int ni = 0; ni < 8; ++ni) {
                int c = ni * 16 + col16;
                float bb = b2[c];
                float2 w3v = *(const float2*)(W3 + c * 2);
                #pragma unroll
                for (int r = 0; r < 4; ++r) {
                    float z = gelu_fast(acc[ni][r] + bb);
                    p0[r] = fmaf(z, w3v.x, p0[r]);
                    p1[r] = fmaf(z, w3v.y, p1[r]);
                }
            }
            #pragma unroll
            for (int r = 0; r < 4; ++r) {
                float s0 = p0[r], s1 = p1[r];
                #pragma unroll
                for (int off = 1; off < 16; off <<= 1) {
                    s0 += __shfl_xor(s0, off);
                    s1 += __shfl_xor(s1, off);
                }
                if (col16 == 0) {
                    float z0 = s0 + b30, z1v = s1 + b31;
                    float m = fmaxf(z0, z1v);
                    float lse = m + __logf(__expf(z0 - m) + __expf(z1v - m));
                    int j = jt * 64 + w * 16 + quad * 4 + r;
                    *(float2*)(out + ((size_t)(b * NQ + iq) * NN + j) * 2) =
                        make_float2(z0 - lse, z1v - lse);
                }
            }
            __syncthreads();   // protect w2s before next tile's prologue
        }
    }
}

extern "C" void kernel_launch(void* const* d_in, const int* in_sizes, int n_in,
                              void* d_out, int out_size, void* d_ws, size_t ws_size,
                              hipStream_t stream) {
    const float* x      = (const float*)d_in[0];
    const float* query  = (const float*)d_in[1];
    const float* policy = (const float*)d_in[2];
    const float* ln_g   = (const float*)d_in[3];
    const float* ln_b   = (const float*)d_in[4];
    const float* W_in   = (const float*)d_in[5];
    const float* b_in   = (const float*)d_in[6];
    const float* W1     = (const float*)d_in[7];
    const float* b1     = (const float*)d_in[8];
    const float* W2     = (const float*)d_in[9];
    const float* b2     = (const float*)d_in[10];
    const float* W3     = (const float*)d_in[11];
    const float* b3     = (const float*)d_in[12];
    float* out = (float*)d_out;

    float* ws    = (float*)d_ws;
    float* At    = ws;                 // 2*1024*256 fp32 (MFMA-A-frag tiled)
    float* Qc    = ws + 524288;        // 200*256
    float* gpart = ws + 575488;        // 512*128
    float* ppart = ws + 641024;        // 512
    short* W2T   = (short*)(ws + 641536);  // 128*256 bf16, MFMA-B-frag tiled

    int nbpc = 0;
    hipOccupancyMaxActiveBlocksPerMultiprocessor(&nbpc, mega, 256, 0);
    if (nbpc < 1) nbpc = 1;
    int grid = nbpc * 256;
    if (grid > 1024) grid = 1024;

    void* args[] = {
        (void*)&x, (void*)&ln_g, (void*)&ln_b, (void*)&W_in, (void*)&b_in,
        (void*)&policy, (void*)&query, (void*)&W1, (void*)&W2, (void*)&b1,
        (void*)&b2, (void*)&W3, (void*)&b3, (void*)&At, (void*)&Qc,
        (void*)&gpart, (void*)&ppart, (void*)&W2T, (void*)&out
    };
    hipLaunchCooperativeKernel((void*)mega, dim3(grid), dim3(256), args, 0, stream);
}

// Round 9
// 275.644 us; speedup vs baseline: 1.1261x; 1.1261x over previous
//
#include <hip/hip_runtime.h>
#include <math.h>

#define BB 2
#define NN 1024
#define CC 256
#define NQ 100
#define HALF 128
#define NPROD 744          // producer blocks: 512 kA + 32 prep + 200 Qc_q
#define GRID 1536
#define NT3 3200           // phase-C tiles

typedef __attribute__((ext_vector_type(8))) short bf16x8;
typedef __attribute__((ext_vector_type(4))) float f32x4;

__device__ __forceinline__ float exp2_fast(float v) {
#if __has_builtin(__builtin_amdgcn_exp2f)
    return __builtin_amdgcn_exp2f(v);
#else
    return __expf(0.69314718056f * v);
#endif
}

// gelu tanh-form: x * sigmoid(2*c1*(x + c2*x^3)); |err vs erf-gelu| <= ~3e-4.
__device__ __forceinline__ float gelu_fast(float x) {
    float x2 = x * x;
    float v = x * fmaf(0.10293942f, x2, 2.30211418f);
    float e = exp2_fast(v);
    float r = __builtin_amdgcn_rcpf(1.0f + e);
    return fmaf(-x, r, x);
}

__device__ __forceinline__ short f2bf(float f) {
    union { float f; unsigned u; } v; v.f = f;
    return (short)((v.u + 0x7FFFu + ((v.u >> 16) & 1u)) >> 16);
}

// flags[0] = phase-A done counter (target NPROD); flags[1+b] = Gterm[b] ready.
__global__ __launch_bounds__(256, 6) void mega(
        const float* __restrict__ x, const float* __restrict__ ln_g,
        const float* __restrict__ ln_b, const float* __restrict__ W_in,
        const float* __restrict__ b_in, const float* __restrict__ policy,
        const float* __restrict__ query, const float* __restrict__ W1,
        const float* __restrict__ W2, const float* __restrict__ b1,
        const float* __restrict__ b2, const float* __restrict__ W3,
        const float* __restrict__ b3, float* __restrict__ At,
        float* __restrict__ Qcq, float* __restrict__ gpart,
        float* __restrict__ ppart, short* __restrict__ W2T,
        float* __restrict__ Gterm, unsigned* __restrict__ flags,
        float* __restrict__ out) {
    __shared__ __align__(16) char smem[16384];
    int t = threadIdx.x;
    int bi = blockIdx.x;

    // ================= phase A (producers: blocks 0..NPROD-1) =================
    if (bi < 512) {
        // kA: LN -> W_in GEMM -> gelu -> gpart/ppart; h_local@W1lo -> At tiled
        float* xst = (float*)smem;             // [256][4]
        float* hst = (float*)(smem + 4096);    // [128][4]
        int wave = t >> 6, lane = t & 63;
        int row0 = bi * 4;
        const float* xr = x + (size_t)(row0 + wave) * CC;
        float v0 = xr[lane], v1 = xr[lane + 64];
        float v2 = xr[lane + 128], v3 = xr[lane + 192];
        float s = v0 + v1 + v2 + v3;
        for (int off = 32; off; off >>= 1) s += __shfl_down(s, off);
        s = __shfl(s, 0);
        float mu = s * (1.0f / CC);
        float d0 = v0 - mu, d1 = v1 - mu, d2 = v2 - mu, d3 = v3 - mu;
        float vs = d0 * d0 + d1 * d1 + d2 * d2 + d3 * d3;
        for (int off = 32; off; off >>= 1) vs += __shfl_down(vs, off);
        vs = __shfl(vs, 0);
        float rstd = rsqrtf(vs * (1.0f / CC) + 1e-5f);
        xst[(lane)*4 + wave]       = d0 * rstd * ln_g[lane]       + ln_b[lane];
        xst[(lane + 64)*4 + wave]  = d1 * rstd * ln_g[lane + 64]  + ln_b[lane + 64];
        xst[(lane + 128)*4 + wave] = d2 * rstd * ln_g[lane + 128] + ln_b[lane + 128];
        xst[(lane + 192)*4 + wave] = d3 * rstd * ln_g[lane + 192] + ln_b[lane + 192];
        __syncthreads();
        float a0 = b_in[t], a1 = a0, a2 = a0, a3 = a0;
        #pragma unroll 8
        for (int k = 0; k < CC; ++k) {
            float4 xv = *(const float4*)&xst[k * 4];  // broadcast
            float wv = W_in[k * CC + t];
            a0 = fmaf(xv.x, wv, a0); a1 = fmaf(xv.y, wv, a1);
            a2 = fmaf(xv.z, wv, a2); a3 = fmaf(xv.w, wv, a3);
        }
        float h0 = gelu_fast(a0), h1 = gelu_fast(a1);
        float h2 = gelu_fast(a2), h3 = gelu_fast(a3);
        float p0 = policy[row0], p1 = policy[row0 + 1];
        float p2 = policy[row0 + 2], p3 = policy[row0 + 3];
        if (t < HALF) {
            hst[t * 4 + 0] = h0; hst[t * 4 + 1] = h1;
            hst[t * 4 + 2] = h2; hst[t * 4 + 3] = h3;
        } else {
            gpart[(size_t)bi * HALF + (t - HALF)] =
                h0 * p0 + h1 * p1 + h2 * p2 + h3 * p3;
        }
        if (t == 0) ppart[bi] = p0 + p1 + p2 + p3;
        __syncthreads();
        float c0 = 0, c1 = 0, c2 = 0, c3 = 0;
        #pragma unroll 8
        for (int k = 0; k < HALF; ++k) {
            float4 hv = *(const float4*)&hst[k * 4];  // broadcast
            float wv = W1[k * CC + t];
            c0 = fmaf(hv.x, wv, c0); c1 = fmaf(hv.y, wv, c1);
            c2 = fmaf(hv.z, wv, c2); c3 = fmaf(hv.w, wv, c3);
        }
        int b = row0 >> 10;
        int lr = row0 & (NN - 1);
        size_t tb = ((size_t)(b * 64 + (lr >> 4)) * 32 + (t >> 3)) * 128 + (t & 7);
        int r16 = lr & 15;
        At[tb + (r16 + 0) * 8] = c0;
        At[tb + (r16 + 1) * 8] = c1;
        At[tb + (r16 + 2) * 8] = c2;
        At[tb + (r16 + 3) * 8] = c3;
    } else if (bi < 544) {
        // W2 -> bf16 MFMA-B-frag tiled W2T
        int u = (bi - 512) * 256 + t;
        int n = u & 127;
        int kq = u >> 7;
        short4 v;
        v.x = f2bf(W2[(kq * 4 + 0) * HALF + n]);
        v.y = f2bf(W2[(kq * 4 + 1) * HALF + n]);
        v.z = f2bf(W2[(kq * 4 + 2) * HALF + n]);
        v.w = f2bf(W2[(kq * 4 + 3) * HALF + n]);
        *(short4*)(W2T + (size_t)((n >> 4) * 32 + (kq >> 1)) * 128
                   + (n & 15) * 8 + (kq & 1) * 4) = v;
    } else if (bi < NPROD) {
        // Qc_q[row] = q[b,i] @ W1[256:512]   (independent of x)
        float* qs = (float*)smem;
        int row = bi - 544;
        int b = row / NQ, i = row % NQ;
        qs[t] = query[(size_t)(i * BB + b) * CC + t];
        __syncthreads();
        float g = 0.f;
        #pragma unroll 8
        for (int k = 0; k < CC; ++k)
            g = fmaf(qs[k], W1[(2 * HALF + k) * CC + t], g);
        Qcq[(size_t)row * CC + t] = g;
    }

    // producers publish (release: waits own stores, flushes L2 for agent scope)
    if (bi < NPROD) {
        __syncthreads();
        if (t == 0)
            __hip_atomic_fetch_add(&flags[0], 1u, __ATOMIC_RELEASE,
                                   __HIP_MEMORY_SCOPE_AGENT);
    }

    // ============ Gterm (blocks 0,1): glob -> Gterm[b], publish flag ============
    if (bi < BB) {
        if (t == 0) {
            while (__hip_atomic_load(&flags[0], __ATOMIC_RELAXED,
                                     __HIP_MEMORY_SCOPE_AGENT) < NPROD)
                __builtin_amdgcn_s_sleep(16);
            (void)__hip_atomic_load(&flags[0], __ATOMIC_ACQUIRE,
                                    __HIP_MEMORY_SCOPE_AGENT);
        }
        __syncthreads();
        float* gl2 = (float*)smem;             // [2][128]
        float* gls = (float*)(smem + 1024);    // [128]
        float* pss = (float*)(smem + 1536);    // [1]
        int b = bi;
        int c = t & 127, hh = t >> 7;
        {
            const float* gp = gpart + ((size_t)b * 256 + hh * 128) * HALF + c;
            float s = 0.f;
            #pragma unroll 16
            for (int ch = 0; ch < 128; ++ch) s += gp[(size_t)ch * HALF];
            gl2[hh * HALF + c] = s;
        }
        if (t < 64) {
            const float* pp = ppart + b * 256;
            float ps = pp[t] + pp[t + 64] + pp[t + 128] + pp[t + 192];
            for (int off = 32; off; off >>= 1) ps += __shfl_down(ps, off);
            if (t == 0) pss[0] = ps;
        }
        __syncthreads();
        if (t < HALF) gls[t] = (gl2[t] + gl2[HALF + t]) / pss[0];
        __syncthreads();
        float g = b1[t];
        #pragma unroll 8
        for (int k = 0; k < HALF; ++k)
            g = fmaf(gls[k], W1[(HALF + k) * CC + t], g);
        Gterm[b * CC + t] = g;
        __syncthreads();
        if (t == 0)
            __hip_atomic_store(&flags[1 + b], 1u, __ATOMIC_RELEASE,
                               __HIP_MEMORY_SCOPE_AGENT);
    }

    // ================= phase C: k5 tiles, grid-strided =================
    // wait for both Gterm flags (implies all At/W2T/Qcq published)
    if (t == 0) {
        while (__hip_atomic_load(&flags[1], __ATOMIC_RELAXED,
                                 __HIP_MEMORY_SCOPE_AGENT) == 0u)
            __builtin_amdgcn_s_sleep(16);
        while (__hip_atomic_load(&flags[2], __ATOMIC_RELAXED,
                                 __HIP_MEMORY_SCOPE_AGENT) == 0u)
            __builtin_amdgcn_s_sleep(16);
        (void)__hip_atomic_load(&flags[2], __ATOMIC_ACQUIRE,
                                __HIP_MEMORY_SCOPE_AGENT);
    }
    __syncthreads();

    {
        short* w2s = (short*)smem;   // [2][4096]
        int lane = t & 63, w = t >> 6;
        int col16 = lane & 15, quad = lane >> 4;
        const short* Wg = W2T + (size_t)((t >> 6) * 32 + ((t >> 4) & 3)) * 128
                          + (t & 15) * 8;
        float b30 = b3[0], b31 = b3[1];
        // remap so idle blocks (744..871) take the 128 extra tiles
        int bi2 = (bi >= NPROD) ? (bi - NPROD) : (bi + (GRID - NPROD));
        for (int blk = bi2; blk < NT3; blk += GRID) {
            int jt = blk & 15;
            int iq = (blk >> 4) % NQ;
            int b  = blk / (16 * NQ);
            const float* Abase = At + ((size_t)(b * 64 + jt * 4 + w) * 32) * 128
                                 + col16 * 8;
            const float* Qrow = Qcq + (size_t)(b * NQ + iq) * CC;
            const float* Grow = Gterm + b * CC;

            f32x4 acc[8];
            #pragma unroll
            for (int ni = 0; ni < 8; ++ni) acc[ni] = (f32x4){0.f, 0.f, 0.f, 0.f};

            bf16x8 nx0 = *(const bf16x8*)(Wg);
            bf16x8 nx1 = *(const bf16x8*)(Wg + 16384);
            float4 a0 = *(const float4*)(Abase + quad * 128);
            float4 a1 = *(const float4*)(Abase + quad * 128 + 4);
            float4 q0 = *(const float4*)(Qrow + quad * 8);
            float4 q1 = *(const float4*)(Qrow + quad * 8 + 4);
            float4 g0 = *(const float4*)(Grow + quad * 8);
            float4 g1 = *(const float4*)(Grow + quad * 8 + 4);
            *(bf16x8*)&w2s[t * 8] = nx0;
            *(bf16x8*)&w2s[2048 + t * 8] = nx1;
            nx0 = *(const bf16x8*)(Wg + 512);
            nx1 = *(const bf16x8*)(Wg + 16384 + 512);
            __syncthreads();

            #pragma unroll
            for (int kt = 0; kt < 8; ++kt) {
                int buf = kt & 1;
                if (kt < 7) {
                    *(bf16x8*)&w2s[(1 - buf) * 4096 + t * 8] = nx0;
                    *(bf16x8*)&w2s[(1 - buf) * 4096 + 2048 + t * 8] = nx1;
                }
                if (kt < 6) {
                    nx0 = *(const bf16x8*)(Wg + (kt + 2) * 512);
                    nx1 = *(const bf16x8*)(Wg + 16384 + (kt + 2) * 512);
                }
                union { bf16x8 v; short s[8]; } fr;
                fr.s[0] = f2bf(gelu_fast(a0.x + q0.x + g0.x));
                fr.s[1] = f2bf(gelu_fast(a0.y + q0.y + g0.y));
                fr.s[2] = f2bf(gelu_fast(a0.z + q0.z + g0.z));
                fr.s[3] = f2bf(gelu_fast(a0.w + q0.w + g0.w));
                fr.s[4] = f2bf(gelu_fast(a1.x + q1.x + g1.x));
                fr.s[5] = f2bf(gelu_fast(a1.y + q1.y + g1.y));
                fr.s[6] = f2bf(gelu_fast(a1.z + q1.z + g1.z));
                fr.s[7] = f2bf(gelu_fast(a1.w + q1.w + g1.w));
                if (kt < 7) {
                    const float* Ap = Abase + (size_t)((kt + 1) * 4 + quad) * 128;
                    a0 = *(const float4*)(Ap);
                    a1 = *(const float4*)(Ap + 4);
                    q0 = *(const float4*)(Qrow + (kt + 1) * 32 + quad * 8);
                    q1 = *(const float4*)(Qrow + (kt + 1) * 32 + quad * 8 + 4);
                    g0 = *(const float4*)(Grow + (kt + 1) * 32 + quad * 8);
                    g1 = *(const float4*)(Grow + (kt + 1) * 32 + quad * 8 + 4);
                }
                #pragma unroll
                for (int ni = 0; ni < 8; ++ni) {
                    bf16x8 bv = *(const bf16x8*)&w2s[buf * 4096 + (ni * 64 + lane) * 8];
                    acc[ni] = __builtin_amdgcn_mfma_f32_16x16x32_bf16(fr.v, bv,
                                                                      acc[ni], 0, 0, 0);
                }
                if (kt < 7) __syncthreads();
            }

            float p0[4] = {0, 0, 0, 0}, p1[4] = {0, 0, 0, 0};
            #pragma unroll
            for (int ni = 0; ni < 8; ++ni) {
                int c = ni * 16 + col16;
                float bb = b2[c];
                float2 w3v = *(const float2*)(W3 + c * 2);
                #pragma unroll
                for (int r = 0; r < 4; ++r) {
                    float z = gelu_fast(acc[ni][r] + bb);
                    p0[r] = fmaf(z, w3v.x, p0[r]);
                    p1[r] = fmaf(z, w3v.y, p1[r]);
                }
            }
            #pragma unroll
            for (int r = 0; r < 4; ++r) {
                float s0 = p0[r], s1 = p1[r];
                #pragma unroll
                for (int off = 1; off < 16; off <<= 1) {
                    s0 += __shfl_xor(s0, off);
                    s1 += __shfl_xor(s1, off);
                }
                if (col16 == 0) {
                    float z0 = s0 + b30, z1v = s1 + b31;
                    float m = fmaxf(z0, z1v);
                    float lse = m + __logf(__expf(z0 - m) + __expf(z1v - m));
                    int j = jt * 64 + w * 16 + quad * 4 + r;
                    *(float2*)(out + ((size_t)(b * NQ + iq) * NN + j) * 2) =
                        make_float2(z0 - lse, z1v - lse);
                }
            }
            __syncthreads();   // protect w2s before next tile's prologue
        }
    }
}

extern "C" void kernel_launch(void* const* d_in, const int* in_sizes, int n_in,
                              void* d_out, int out_size, void* d_ws, size_t ws_size,
                              hipStream_t stream) {
    const float* x      = (const float*)d_in[0];
    const float* query  = (const float*)d_in[1];
    const float* policy = (const float*)d_in[2];
    const float* ln_g   = (const float*)d_in[3];
    const float* ln_b   = (const float*)d_in[4];
    const float* W_in   = (const float*)d_in[5];
    const float* b_in   = (const float*)d_in[6];
    const float* W1     = (const float*)d_in[7];
    const float* b1     = (const float*)d_in[8];
    const float* W2     = (const float*)d_in[9];
    const float* b2     = (const float*)d_in[10];
    const float* W3     = (const float*)d_in[11];
    const float* b3     = (const float*)d_in[12];
    float* out = (float*)d_out;

    float*    ws    = (float*)d_ws;
    float*    At    = ws;                      // 524288 floats
    float*    Qcq   = ws + 524288;             // 51200
    float*    gpart = ws + 575488;             // 65536
    float*    ppart = ws + 641024;             // 512
    short*    W2T   = (short*)(ws + 641536);   // 32768 shorts (16384 floats)
    float*    Gterm = ws + 657920;             // 512
    unsigned* flags = (unsigned*)(ws + 658432); // 3 words

    hipMemsetAsync(flags, 0, 16, stream);

    mega<<<GRID, 256, 0, stream>>>(x, ln_g, ln_b, W_in, b_in, policy, query,
                                   W1, W2, b1, b2, W3, b3, At, Qcq, gpart,
                                   ppart, W2T, Gterm, flags, out);
}

// Round 10
// 167.411 us; speedup vs baseline: 1.8542x; 1.6465x over previous
//
#include <hip/hip_runtime.h>
#include <hip/hip_bf16.h>
#include <math.h>

#define BB 2
#define NN 1024
#define CC 256
#define NQ 100
#define HALF 128

typedef __attribute__((ext_vector_type(8))) short bf16x8;
typedef __attribute__((ext_vector_type(4))) float f32x4;

__device__ __forceinline__ float exp2_fast(float v) {
#if __has_builtin(__builtin_amdgcn_exp2f)
    return __builtin_amdgcn_exp2f(v);
#else
    return __expf(0.69314718056f * v);
#endif
}

// gelu tanh-form: x * sigmoid(2*c1*(x + c2*x^3)); |err vs erf-gelu| <= ~3e-4.
__device__ __forceinline__ float gelu_fast(float x) {
    float x2 = x * x;
    float v = x * fmaf(0.10293942f, x2, 2.30211418f);
    float e = exp2_fast(v);
    float r = __builtin_amdgcn_rcpf(1.0f + e);
    return fmaf(-x, r, x);
}

__device__ __forceinline__ short f2bf(float f) {
    union { float f; unsigned u; } v; v.f = f;
    return (short)((v.u + 0x7FFFu + ((v.u >> 16) & 1u)) >> 16);
}

// ---- kA: LN -> W_in GEMM -> gelu -> gpart/ppart; h_local@W1lo -> At tiled ----
// At layout: At[((b*64 + row/16)*32 + k/8)*128 + (row%16)*8 + k%8].
__global__ __launch_bounds__(256) void kA_fused(
        const float* __restrict__ x, const float* __restrict__ ln_g,
        const float* __restrict__ ln_b, const float* __restrict__ W_in,
        const float* __restrict__ b_in, const float* __restrict__ policy,
        const float* __restrict__ W1, float* __restrict__ At,
        float* __restrict__ gpart, float* __restrict__ ppart) {
    __shared__ float xst[CC][4];
    __shared__ float hst[HALF][4];
    int t = threadIdx.x;
    int wave = t >> 6, lane = t & 63;
    int blk = blockIdx.x;
    int row0 = blk * 4;
    const float* xr = x + (size_t)(row0 + wave) * CC;
    float v0 = xr[lane], v1 = xr[lane + 64], v2 = xr[lane + 128], v3 = xr[lane + 192];
    float s = v0 + v1 + v2 + v3;
    for (int off = 32; off; off >>= 1) s += __shfl_down(s, off);
    s = __shfl(s, 0);
    float mu = s * (1.0f / CC);
    float d0 = v0 - mu, d1 = v1 - mu, d2 = v2 - mu, d3 = v3 - mu;
    float vs = d0 * d0 + d1 * d1 + d2 * d2 + d3 * d3;
    for (int off = 32; off; off >>= 1) vs += __shfl_down(vs, off);
    vs = __shfl(vs, 0);
    float rstd = rsqrtf(vs * (1.0f / CC) + 1e-5f);
    xst[lane][wave]       = d0 * rstd * ln_g[lane]       + ln_b[lane];
    xst[lane + 64][wave]  = d1 * rstd * ln_g[lane + 64]  + ln_b[lane + 64];
    xst[lane + 128][wave] = d2 * rstd * ln_g[lane + 128] + ln_b[lane + 128];
    xst[lane + 192][wave] = d3 * rstd * ln_g[lane + 192] + ln_b[lane + 192];
    __syncthreads();
    float a0 = b_in[t], a1 = a0, a2 = a0, a3 = a0;
    #pragma unroll 8
    for (int k = 0; k < CC; ++k) {
        float4 xv = *(const float4*)xst[k];     // uniform addr -> broadcast
        float wv = W_in[k * CC + t];
        a0 = fmaf(xv.x, wv, a0); a1 = fmaf(xv.y, wv, a1);
        a2 = fmaf(xv.z, wv, a2); a3 = fmaf(xv.w, wv, a3);
    }
    float h0 = gelu_fast(a0), h1 = gelu_fast(a1);
    float h2 = gelu_fast(a2), h3 = gelu_fast(a3);
    float p0 = policy[row0], p1 = policy[row0 + 1];
    float p2 = policy[row0 + 2], p3 = policy[row0 + 3];
    if (t < HALF) {
        hst[t][0] = h0; hst[t][1] = h1; hst[t][2] = h2; hst[t][3] = h3;
    } else {
        gpart[(size_t)blk * HALF + (t - HALF)] =
            h0 * p0 + h1 * p1 + h2 * p2 + h3 * p3;
    }
    if (t == 0) ppart[blk] = p0 + p1 + p2 + p3;
    __syncthreads();
    float c0 = 0, c1 = 0, c2 = 0, c3 = 0;
    #pragma unroll 8
    for (int k = 0; k < HALF; ++k) {
        float4 hv = *(const float4*)hst[k];     // uniform addr -> broadcast
        float wv = W1[k * CC + t];
        c0 = fmaf(hv.x, wv, c0); c1 = fmaf(hv.y, wv, c1);
        c2 = fmaf(hv.z, wv, c2); c3 = fmaf(hv.w, wv, c3);
    }
    int b = row0 >> 10;
    int lr = row0 & (NN - 1);
    size_t tb = ((size_t)(b * 64 + (lr >> 4)) * 32 + (t >> 3)) * 128 + (t & 7);
    int r16 = lr & 15;
    At[tb + (r16 + 0) * 8] = c0;
    At[tb + (r16 + 1) * 8] = c1;
    At[tb + (r16 + 2) * 8] = c2;
    At[tb + (r16 + 3) * 8] = c3;
}

// ---- kB: blocks 0..199: Qc = q@W1hi + glob@W1mid + b1 (glob from gpart);
//      blocks 200..231: W2 -> bf16 MFMA-B-frag tiled W2T. ----
__global__ __launch_bounds__(256) void kB_qc_prep(
        const float* __restrict__ query, const float* __restrict__ W1,
        const float* __restrict__ W2, const float* __restrict__ gpart,
        const float* __restrict__ ppart, const float* __restrict__ b1,
        float* __restrict__ Qc, short* __restrict__ W2T) {
    int blk = blockIdx.x, t = threadIdx.x;
    if (blk >= BB * NQ) {
        int u = (blk - BB * NQ) * 256 + t;
        int n = u & 127;
        int kq = u >> 7;
        short4 v;
        v.x = f2bf(W2[(kq * 4 + 0) * HALF + n]);
        v.y = f2bf(W2[(kq * 4 + 1) * HALF + n]);
        v.z = f2bf(W2[(kq * 4 + 2) * HALF + n]);
        v.w = f2bf(W2[(kq * 4 + 3) * HALF + n]);
        *(short4*)(W2T + (size_t)((n >> 4) * 32 + (kq >> 1)) * 128
                   + (n & 15) * 8 + (kq & 1) * 4) = v;
        return;
    }
    __shared__ float gl2[2][HALF];
    __shared__ float gls[HALF];
    __shared__ float qs[CC];
    __shared__ float pss;
    int b = blk / NQ, i = blk % NQ;
    int c = t & 127, hh = t >> 7;
    {
        const float* gp = gpart + ((size_t)b * 256 + hh * 128) * HALF + c;
        float s = 0.f;
        #pragma unroll 16
        for (int ch = 0; ch < 128; ++ch) s += gp[(size_t)ch * HALF];
        gl2[hh][c] = s;
    }
    if (t < 64) {
        const float* pp = ppart + b * 256;
        float ps = pp[t] + pp[t + 64] + pp[t + 128] + pp[t + 192];
        for (int off = 32; off; off >>= 1) ps += __shfl_down(ps, off);
        if (t == 0) pss = ps;
    }
    qs[t] = query[(size_t)(i * BB + b) * CC + t];
    __syncthreads();
    if (t < HALF) gls[t] = (gl2[0][t] + gl2[1][t]) / pss;
    __syncthreads();
    float g = b1[t];
    #pragma unroll 8
    for (int k = 0; k < HALF; ++k)
        g = fmaf(gls[k], W1[(HALF + k) * CC + t], g);
    #pragma unroll 8
    for (int k = 0; k < CC; ++k)
        g = fmaf(qs[k], W1[(2 * HALF + k) * CC + t], g);
    Qc[(size_t)blk * CC + t] = g;
}

// ---- k5: block tile M=128 x N=128; 4 waves, wave-tile m=32 x n=128 (acc 64).
// z1 frags in-register from tiled At; W2 per-32k chunk in frag-tiled dbuf LDS
// (conflict-free); 8 DS-reads serve 16 MFMAs per kt. 1600 tiles, split by
// parity into two 800-block dispatches (all-resident; exposes kA/kB in top-5).
__global__ __launch_bounds__(256, 4) void k5_main(
        const float* __restrict__ At, const float* __restrict__ Qc,
        const short* __restrict__ W2T, const float* __restrict__ b2,
        const float* __restrict__ W3, const float* __restrict__ b3,
        float* __restrict__ out, int parity) {
    __shared__ short w2s[2][4096];   // 2 x 8 KB

    int t = threadIdx.x;
    int lane = t & 63, w = t >> 6;
    int col16 = lane & 15, quad = lane >> 4;
    int blk = blockIdx.x * 2 + parity;   // 0..1599
    int jt = blk & 7;                    // 8 j-tiles of 128 rows
    int iq = (blk >> 3) % NQ;
    int b  = blk / (8 * NQ);
    // row-group (16 rows) index: b*64 + jt*8 + w*2 + mi
    const float* A0 = At + (size_t)(b * 64 + jt * 8 + w * 2) * 4096 + col16 * 8;
    const float* Qrow = Qc + (size_t)(b * NQ + iq) * CC;
    const short* Wg = W2T + (size_t)((t >> 6) * 32 + ((t >> 4) & 3)) * 128
                      + (t & 15) * 8;

    f32x4 acc[2][8];
    #pragma unroll
    for (int mi = 0; mi < 2; ++mi)
        #pragma unroll
        for (int ni = 0; ni < 8; ++ni)
            acc[mi][ni] = (f32x4){0.f, 0.f, 0.f, 0.f};

    // prologue: chunk0 -> buf0; chunk1 -> regs; A/Q(kt=0) -> regs
    bf16x8 nx0 = *(const bf16x8*)(Wg);
    bf16x8 nx1 = *(const bf16x8*)(Wg + 16384);
    float4 a00 = *(const float4*)(A0 + quad * 128);
    float4 a01 = *(const float4*)(A0 + quad * 128 + 4);
    float4 a10 = *(const float4*)(A0 + 4096 + quad * 128);
    float4 a11 = *(const float4*)(A0 + 4096 + quad * 128 + 4);
    float4 q0 = *(const float4*)(Qrow + quad * 8);
    float4 q1 = *(const float4*)(Qrow + quad * 8 + 4);
    *(bf16x8*)&w2s[0][t * 8] = nx0;
    *(bf16x8*)&w2s[0][2048 + t * 8] = nx1;
    nx0 = *(const bf16x8*)(Wg + 512);
    nx1 = *(const bf16x8*)(Wg + 16384 + 512);
    __syncthreads();

    #pragma unroll
    for (int kt = 0; kt < 8; ++kt) {
        int buf = kt & 1;
        if (kt < 7) {
            *(bf16x8*)&w2s[1 - buf][t * 8] = nx0;
            *(bf16x8*)&w2s[1 - buf][2048 + t * 8] = nx1;
        }
        if (kt < 6) {
            nx0 = *(const bf16x8*)(Wg + (kt + 2) * 512);
            nx1 = *(const bf16x8*)(Wg + 16384 + (kt + 2) * 512);
        }
        // z1 frags for both row-groups (packed bf16 cvt)
        union { bf16x8 v; __hip_bfloat162 h[4]; } f0, f1;
        f0.h[0] = __float22bfloat162_rn(make_float2(gelu_fast(a00.x + q0.x),
                                                   gelu_fast(a00.y + q0.y)));
        f0.h[1] = __float22bfloat162_rn(make_float2(gelu_fast(a00.z + q0.z),
                                                   gelu_fast(a00.w + q0.w)));
        f0.h[2] = __float22bfloat162_rn(make_float2(gelu_fast(a01.x + q1.x),
                                                   gelu_fast(a01.y + q1.y)));
        f0.h[3] = __float22bfloat162_rn(make_float2(gelu_fast(a01.z + q1.z),
                                                   gelu_fast(a01.w + q1.w)));
        f1.h[0] = __float22bfloat162_rn(make_float2(gelu_fast(a10.x + q0.x),
                                                   gelu_fast(a10.y + q0.y)));
        f1.h[1] = __float22bfloat162_rn(make_float2(gelu_fast(a10.z + q0.z),
                                                   gelu_fast(a10.w + q0.w)));
        f1.h[2] = __float22bfloat162_rn(make_float2(gelu_fast(a11.x + q1.x),
                                                   gelu_fast(a11.y + q1.y)));
        f1.h[3] = __float22bfloat162_rn(make_float2(gelu_fast(a11.z + q1.z),
                                                   gelu_fast(a11.w + q1.w)));
        if (kt < 7) {
            const float* Ap = A0 + (size_t)((kt + 1) * 4 + quad) * 128;
            a00 = *(const float4*)(Ap);
            a01 = *(const float4*)(Ap + 4);
            a10 = *(const float4*)(Ap + 4096);
            a11 = *(const float4*)(Ap + 4096 + 4);
            q0 = *(const float4*)(Qrow + (kt + 1) * 32 + quad * 8);
            q1 = *(const float4*)(Qrow + (kt + 1) * 32 + quad * 8 + 4);
        }
        #pragma unroll
        for (int ni = 0; ni < 8; ++ni) {
            bf16x8 bv = *(const bf16x8*)&w2s[buf][(ni * 64 + lane) * 8];
            acc[0][ni] = __builtin_amdgcn_mfma_f32_16x16x32_bf16(f0.v, bv,
                                                                 acc[0][ni], 0, 0, 0);
            acc[1][ni] = __builtin_amdgcn_mfma_f32_16x16x32_bf16(f1.v, bv,
                                                                 acc[1][ni], 0, 0, 0);
        }
        if (kt < 7) __syncthreads();
    }

    // epilogue: z2 = gelu(acc + b2); logits = z2@W3; reduce over col16; lsm
    float b30 = b3[0], b31 = b3[1];
    #pragma unroll
    for (int mi = 0; mi < 2; ++mi) {
        float p0[4] = {0, 0, 0, 0}, p1[4] = {0, 0, 0, 0};
        #pragma unroll
        for (int ni = 0; ni < 8; ++ni) {
            int c = ni * 16 + col16;
            float bb = b2[c];
            float2 w3v = *(const float2*)(W3 + c * 2);
            #pragma unroll
            for (int r = 0; r < 4; ++r) {
                float z = gelu_fast(acc[mi][ni][r] + bb);
                p0[r] = fmaf(z, w3v.x, p0[r]);
                p1[r] = fmaf(z, w3v.y, p1[r]);
            }
        }
        #pragma unroll
        for (int r = 0; r < 4; ++r) {
            float s0 = p0[r], s1 = p1[r];
            #pragma unroll
            for (int off = 1; off < 16; off <<= 1) {
                s0 += __shfl_xor(s0, off);
                s1 += __shfl_xor(s1, off);
            }
            if (col16 == 0) {
                float z0 = s0 + b30, z1v = s1 + b31;
                float m = fmaxf(z0, z1v);
                float lse = m + __logf(__expf(z0 - m) + __expf(z1v - m));
                int j = jt * 128 + w * 32 + mi * 16 + quad * 4 + r;
                *(float2*)(out + ((size_t)(b * NQ + iq) * NN + j) * 2) =
                    make_float2(z0 - lse, z1v - lse);
            }
        }
    }
}

extern "C" void kernel_launch(void* const* d_in, const int* in_sizes, int n_in,
                              void* d_out, int out_size, void* d_ws, size_t ws_size,
                              hipStream_t stream) {
    const float* x      = (const float*)d_in[0];
    const float* query  = (const float*)d_in[1];
    const float* policy = (const float*)d_in[2];
    const float* ln_g   = (const float*)d_in[3];
    const float* ln_b   = (const float*)d_in[4];
    const float* W_in   = (const float*)d_in[5];
    const float* b_in   = (const float*)d_in[6];
    const float* W1     = (const float*)d_in[7];
    const float* b1     = (const float*)d_in[8];
    const float* W2     = (const float*)d_in[9];
    const float* b2     = (const float*)d_in[10];
    const float* W3     = (const float*)d_in[11];
    const float* b3     = (const float*)d_in[12];
    float* out = (float*)d_out;

    float* ws    = (float*)d_ws;
    float* At    = ws;                 // 2*1024*256 fp32 (MFMA-A-frag tiled)
    float* Qc    = ws + 524288;        // 200*256
    float* gpart = ws + 575488;        // 512*128
    float* ppart = ws + 641024;        // 512
    short* W2T   = (short*)(ws + 641536);  // 128*256 bf16, MFMA-B-frag tiled

    kA_fused<<<512, 256, 0, stream>>>(x, ln_g, ln_b, W_in, b_in, policy,
                                      W1, At, gpart, ppart);
    kB_qc_prep<<<BB * NQ + 32, 256, 0, stream>>>(query, W1, W2, gpart, ppart,
                                                 b1, Qc, W2T);
    k5_main<<<800, 256, 0, stream>>>(At, Qc, W2T, b2, W3, b3, out, 0);
    k5_main<<<800, 256, 0, stream>>>(At, Qc, W2T, b2, W3, b3, out, 1);
}

// Round 11
// 153.678 us; speedup vs baseline: 2.0199x; 1.0894x over previous
//
#include <hip/hip_runtime.h>
#include <hip/hip_bf16.h>
#include <math.h>

#define BB 2
#define NN 1024
#define CC 256
#define NQ 100
#define HALF 128

typedef __attribute__((ext_vector_type(8))) short bf16x8;
typedef __attribute__((ext_vector_type(4))) float f32x4;

__device__ __forceinline__ float exp2_fast(float v) {
#if __has_builtin(__builtin_amdgcn_exp2f)
    return __builtin_amdgcn_exp2f(v);
#else
    return __expf(0.69314718056f * v);
#endif
}

// gelu tanh-form: x * sigmoid(2*c1*(x + c2*x^3)); |err vs erf-gelu| <= ~3e-4.
__device__ __forceinline__ float gelu_fast(float x) {
    float x2 = x * x;
    float v = x * fmaf(0.10293942f, x2, 2.30211418f);
    float e = exp2_fast(v);
    float r = __builtin_amdgcn_rcpf(1.0f + e);
    return fmaf(-x, r, x);
}

__device__ __forceinline__ short f2bf(float f) {
    union { float f; unsigned u; } v; v.f = f;
    return (short)((v.u + 0x7FFFu + ((v.u >> 16) & 1u)) >> 16);
}

// ---- kA: all independent producers in one dispatch.
//   blocks 0..511:   LN -> W_in GEMM -> gelu -> gpart/ppart; h@W1lo -> At tiled
//   blocks 512..711: Qcq[row] = q[b,i] @ W1[256:512]
//   blocks 712..743: W2 -> bf16 MFMA-B-frag tiled W2T
// At layout: At[((b*64 + row/16)*32 + k/8)*128 + (row%16)*8 + k%8].
__global__ __launch_bounds__(256) void kA_fused(
        const float* __restrict__ x, const float* __restrict__ ln_g,
        const float* __restrict__ ln_b, const float* __restrict__ W_in,
        const float* __restrict__ b_in, const float* __restrict__ policy,
        const float* __restrict__ query, const float* __restrict__ W1,
        const float* __restrict__ W2, float* __restrict__ At,
        float* __restrict__ Qcq, float* __restrict__ gpart,
        float* __restrict__ ppart, short* __restrict__ W2T) {
    __shared__ float xst[CC][4];
    __shared__ float hst[HALF][4];
    int t = threadIdx.x;
    int blk = blockIdx.x;
    if (blk >= 712) {
        // W2 -> bf16 MFMA-B-frag tiling (coalesced reads)
        int u = (blk - 712) * 256 + t;
        int n = u & 127;
        int kq = u >> 7;
        short4 v;
        v.x = f2bf(W2[(kq * 4 + 0) * HALF + n]);
        v.y = f2bf(W2[(kq * 4 + 1) * HALF + n]);
        v.z = f2bf(W2[(kq * 4 + 2) * HALF + n]);
        v.w = f2bf(W2[(kq * 4 + 3) * HALF + n]);
        *(short4*)(W2T + (size_t)((n >> 4) * 32 + (kq >> 1)) * 128
                   + (n & 15) * 8 + (kq & 1) * 4) = v;
        return;
    }
    if (blk >= 512) {
        // Qcq = q @ W1[256:512]
        float* qs = (float*)xst;
        int row = blk - 512;
        int b = row / NQ, i = row % NQ;
        qs[t] = query[(size_t)(i * BB + b) * CC + t];
        __syncthreads();
        float g = 0.f;
        #pragma unroll 8
        for (int k = 0; k < CC; ++k)
            g = fmaf(qs[k], W1[(2 * HALF + k) * CC + t], g);
        Qcq[(size_t)row * CC + t] = g;
        return;
    }
    int wave = t >> 6, lane = t & 63;
    int row0 = blk * 4;
    const float* xr = x + (size_t)(row0 + wave) * CC;
    float v0 = xr[lane], v1 = xr[lane + 64], v2 = xr[lane + 128], v3 = xr[lane + 192];
    float s = v0 + v1 + v2 + v3;
    for (int off = 32; off; off >>= 1) s += __shfl_down(s, off);
    s = __shfl(s, 0);
    float mu = s * (1.0f / CC);
    float d0 = v0 - mu, d1 = v1 - mu, d2 = v2 - mu, d3 = v3 - mu;
    float vs = d0 * d0 + d1 * d1 + d2 * d2 + d3 * d3;
    for (int off = 32; off; off >>= 1) vs += __shfl_down(vs, off);
    vs = __shfl(vs, 0);
    float rstd = rsqrtf(vs * (1.0f / CC) + 1e-5f);
    xst[lane][wave]       = d0 * rstd * ln_g[lane]       + ln_b[lane];
    xst[lane + 64][wave]  = d1 * rstd * ln_g[lane + 64]  + ln_b[lane + 64];
    xst[lane + 128][wave] = d2 * rstd * ln_g[lane + 128] + ln_b[lane + 128];
    xst[lane + 192][wave] = d3 * rstd * ln_g[lane + 192] + ln_b[lane + 192];
    __syncthreads();
    float a0 = b_in[t], a1 = a0, a2 = a0, a3 = a0;
    #pragma unroll 8
    for (int k = 0; k < CC; ++k) {
        float4 xv = *(const float4*)xst[k];     // uniform addr -> broadcast
        float wv = W_in[k * CC + t];
        a0 = fmaf(xv.x, wv, a0); a1 = fmaf(xv.y, wv, a1);
        a2 = fmaf(xv.z, wv, a2); a3 = fmaf(xv.w, wv, a3);
    }
    float h0 = gelu_fast(a0), h1 = gelu_fast(a1);
    float h2 = gelu_fast(a2), h3 = gelu_fast(a3);
    float p0 = policy[row0], p1 = policy[row0 + 1];
    float p2 = policy[row0 + 2], p3 = policy[row0 + 3];
    if (t < HALF) {
        hst[t][0] = h0; hst[t][1] = h1; hst[t][2] = h2; hst[t][3] = h3;
    } else {
        gpart[(size_t)blk * HALF + (t - HALF)] =
            h0 * p0 + h1 * p1 + h2 * p2 + h3 * p3;
    }
    if (t == 0) ppart[blk] = p0 + p1 + p2 + p3;
    __syncthreads();
    float c0 = 0, c1 = 0, c2 = 0, c3 = 0;
    #pragma unroll 8
    for (int k = 0; k < HALF; ++k) {
        float4 hv = *(const float4*)hst[k];     // uniform addr -> broadcast
        float wv = W1[k * CC + t];
        c0 = fmaf(hv.x, wv, c0); c1 = fmaf(hv.y, wv, c1);
        c2 = fmaf(hv.z, wv, c2); c3 = fmaf(hv.w, wv, c3);
    }
    int b = row0 >> 10;
    int lr = row0 & (NN - 1);
    size_t tb = ((size_t)(b * 64 + (lr >> 4)) * 32 + (t >> 3)) * 128 + (t & 7);
    int r16 = lr & 15;
    At[tb + (r16 + 0) * 8] = c0;
    At[tb + (r16 + 1) * 8] = c1;
    At[tb + (r16 + 2) * 8] = c2;
    At[tb + (r16 + 3) * 8] = c3;
}

// ---- kB: 2 blocks. glob = (Σ gpart)/(Σ ppart); Gterm[b] = b1 + glob@W1mid. ----
__global__ __launch_bounds__(256) void kB_gterm(
        const float* __restrict__ W1, const float* __restrict__ gpart,
        const float* __restrict__ ppart, const float* __restrict__ b1,
        float* __restrict__ Gterm) {
    __shared__ float gl2[2][HALF];
    __shared__ float gls[HALF];
    __shared__ float pss;
    int b = blockIdx.x, t = threadIdx.x;
    int c = t & 127, hh = t >> 7;
    {
        const float* gp = gpart + ((size_t)b * 256 + hh * 128) * HALF + c;
        float s = 0.f;
        #pragma unroll 16
        for (int ch = 0; ch < 128; ++ch) s += gp[(size_t)ch * HALF];
        gl2[hh][c] = s;
    }
    if (t < 64) {
        const float* pp = ppart + b * 256;
        float ps = pp[t] + pp[t + 64] + pp[t + 128] + pp[t + 192];
        for (int off = 32; off; off >>= 1) ps += __shfl_down(ps, off);
        if (t == 0) pss = ps;
    }
    __syncthreads();
    if (t < HALF) gls[t] = (gl2[0][t] + gl2[1][t]) / pss;
    __syncthreads();
    float g = b1[t];
    #pragma unroll 8
    for (int k = 0; k < HALF; ++k)
        g = fmaf(gls[k], W1[(HALF + k) * CC + t], g);
    Gterm[b * CC + t] = g;
}

// ---- k5: block tile M=128 x N=128; 4 waves, wave-tile m=32 x n=128 (acc 64).
// z1 = gelu(At + Qcq + Gterm) in-register; W2 per-32k chunk in frag-tiled dbuf
// LDS (conflict-free, 8 DS-reads serve 16 MFMAs); single 1600-block dispatch. ----
__global__ __launch_bounds__(256, 4) void k5_main(
        const float* __restrict__ At, const float* __restrict__ Qcq,
        const float* __restrict__ Gterm, const short* __restrict__ W2T,
        const float* __restrict__ b2, const float* __restrict__ W3,
        const float* __restrict__ b3, float* __restrict__ out) {
    __shared__ short w2s[2][4096];   // 2 x 8 KB

    int t = threadIdx.x;
    int lane = t & 63, w = t >> 6;
    int col16 = lane & 15, quad = lane >> 4;
    int blk = blockIdx.x;                // 0..1599
    int jt = blk & 7;                    // 8 j-tiles of 128 rows
    int iq = (blk >> 3) % NQ;
    int b  = blk / (8 * NQ);
    const float* A0 = At + (size_t)(b * 64 + jt * 8 + w * 2) * 4096 + col16 * 8;
    const float* Qrow = Qcq + (size_t)(b * NQ + iq) * CC;
    const float* Grow = Gterm + b * CC;
    const short* Wg = W2T + (size_t)((t >> 6) * 32 + ((t >> 4) & 3)) * 128
                      + (t & 15) * 8;

    f32x4 acc[2][8];
    #pragma unroll
    for (int mi = 0; mi < 2; ++mi)
        #pragma unroll
        for (int ni = 0; ni < 8; ++ni)
            acc[mi][ni] = (f32x4){0.f, 0.f, 0.f, 0.f};

    // prologue: chunk0 -> buf0; chunk1 -> regs; A/Q/G(kt=0) -> regs
    bf16x8 nx0 = *(const bf16x8*)(Wg);
    bf16x8 nx1 = *(const bf16x8*)(Wg + 16384);
    float4 a00 = *(const float4*)(A0 + quad * 128);
    float4 a01 = *(const float4*)(A0 + quad * 128 + 4);
    float4 a10 = *(const float4*)(A0 + 4096 + quad * 128);
    float4 a11 = *(const float4*)(A0 + 4096 + quad * 128 + 4);
    float4 q0 = *(const float4*)(Qrow + quad * 8);
    float4 q1 = *(const float4*)(Qrow + quad * 8 + 4);
    float4 g0 = *(const float4*)(Grow + quad * 8);
    float4 g1 = *(const float4*)(Grow + quad * 8 + 4);
    *(bf16x8*)&w2s[0][t * 8] = nx0;
    *(bf16x8*)&w2s[0][2048 + t * 8] = nx1;
    nx0 = *(const bf16x8*)(Wg + 512);
    nx1 = *(const bf16x8*)(Wg + 16384 + 512);
    __syncthreads();

    #pragma unroll
    for (int kt = 0; kt < 8; ++kt) {
        int buf = kt & 1;
        if (kt < 7) {
            *(bf16x8*)&w2s[1 - buf][t * 8] = nx0;
            *(bf16x8*)&w2s[1 - buf][2048 + t * 8] = nx1;
        }
        if (kt < 6) {
            nx0 = *(const bf16x8*)(Wg + (kt + 2) * 512);
            nx1 = *(const bf16x8*)(Wg + 16384 + (kt + 2) * 512);
        }
        float qg0x = q0.x + g0.x, qg0y = q0.y + g0.y;
        float qg0z = q0.z + g0.z, qg0w = q0.w + g0.w;
        float qg1x = q1.x + g1.x, qg1y = q1.y + g1.y;
        float qg1z = q1.z + g1.z, qg1w = q1.w + g1.w;
        union { bf16x8 v; __hip_bfloat162 h[4]; } f0, f1;
        f0.h[0] = __float22bfloat162_rn(make_float2(gelu_fast(a00.x + qg0x),
                                                   gelu_fast(a00.y + qg0y)));
        f0.h[1] = __float22bfloat162_rn(make_float2(gelu_fast(a00.z + qg0z),
                                                   gelu_fast(a00.w + qg0w)));
        f0.h[2] = __float22bfloat162_rn(make_float2(gelu_fast(a01.x + qg1x),
                                                   gelu_fast(a01.y + qg1y)));
        f0.h[3] = __float22bfloat162_rn(make_float2(gelu_fast(a01.z + qg1z),
                                                   gelu_fast(a01.w + qg1w)));
        f1.h[0] = __float22bfloat162_rn(make_float2(gelu_fast(a10.x + qg0x),
                                                   gelu_fast(a10.y + qg0y)));
        f1.h[1] = __float22bfloat162_rn(make_float2(gelu_fast(a10.z + qg0z),
                                                   gelu_fast(a10.w + qg0w)));
        f1.h[2] = __float22bfloat162_rn(make_float2(gelu_fast(a11.x + qg1x),
                                                   gelu_fast(a11.y + qg1y)));
        f1.h[3] = __float22bfloat162_rn(make_float2(gelu_fast(a11.z + qg1z),
                                                   gelu_fast(a11.w + qg1w)));
        if (kt < 7) {
            const float* Ap = A0 + (size_t)((kt + 1) * 4 + quad) * 128;
            a00 = *(const float4*)(Ap);
            a01 = *(const float4*)(Ap + 4);
            a10 = *(const float4*)(Ap + 4096);
            a11 = *(const float4*)(Ap + 4096 + 4);
            q0 = *(const float4*)(Qrow + (kt + 1) * 32 + quad * 8);
            q1 = *(const float4*)(Qrow + (kt + 1) * 32 + quad * 8 + 4);
            g0 = *(const float4*)(Grow + (kt + 1) * 32 + quad * 8);
            g1 = *(const float4*)(Grow + (kt + 1) * 32 + quad * 8 + 4);
        }
        #pragma unroll
        for (int ni = 0; ni < 8; ++ni) {
            bf16x8 bv = *(const bf16x8*)&w2s[buf][(ni * 64 + lane) * 8];
            acc[0][ni] = __builtin_amdgcn_mfma_f32_16x16x32_bf16(f0.v, bv,
                                                                 acc[0][ni], 0, 0, 0);
            acc[1][ni] = __builtin_amdgcn_mfma_f32_16x16x32_bf16(f1.v, bv,
                                                                 acc[1][ni], 0, 0, 0);
        }
        if (kt < 7) __syncthreads();
    }

    // epilogue: z2 = gelu(acc + b2); logits = z2@W3; reduce over col16; lsm
    float b30 = b3[0], b31 = b3[1];
    #pragma unroll
    for (int mi = 0; mi < 2; ++mi) {
        float p0[4] = {0, 0, 0, 0}, p1[4] = {0, 0, 0, 0};
        #pragma unroll
        for (int ni = 0; ni < 8; ++ni) {
            int c = ni * 16 + col16;
            float bb = b2[c];
            float2 w3v = *(const float2*)(W3 + c * 2);
            #pragma unroll
            for (int r = 0; r < 4; ++r) {
                float z = gelu_fast(acc[mi][ni][r] + bb);
                p0[r] = fmaf(z, w3v.x, p0[r]);
                p1[r] = fmaf(z, w3v.y, p1[r]);
            }
        }
        #pragma unroll
        for (int r = 0; r < 4; ++r) {
            float s0 = p0[r], s1 = p1[r];
            #pragma unroll
            for (int off = 1; off < 16; off <<= 1) {
                s0 += __shfl_xor(s0, off);
                s1 += __shfl_xor(s1, off);
            }
            if (col16 == 0) {
                float z0 = s0 + b30, z1v = s1 + b31;
                float m = fmaxf(z0, z1v);
                float lse = m + __logf(__expf(z0 - m) + __expf(z1v - m));
                int j = jt * 128 + w * 32 + mi * 16 + quad * 4 + r;
                *(float2*)(out + ((size_t)(b * NQ + iq) * NN + j) * 2) =
                    make_float2(z0 - lse, z1v - lse);
            }
        }
    }
}

extern "C" void kernel_launch(void* const* d_in, const int* in_sizes, int n_in,
                              void* d_out, int out_size, void* d_ws, size_t ws_size,
                              hipStream_t stream) {
    const float* x      = (const float*)d_in[0];
    const float* query  = (const float*)d_in[1];
    const float* policy = (const float*)d_in[2];
    const float* ln_g   = (const float*)d_in[3];
    const float* ln_b   = (const float*)d_in[4];
    const float* W_in   = (const float*)d_in[5];
    const float* b_in   = (const float*)d_in[6];
    const float* W1     = (const float*)d_in[7];
    const float* b1     = (const float*)d_in[8];
    const float* W2     = (const float*)d_in[9];
    const float* b2     = (const float*)d_in[10];
    const float* W3     = (const float*)d_in[11];
    const float* b3     = (const float*)d_in[12];
    float* out = (float*)d_out;

    float* ws    = (float*)d_ws;
    float* At    = ws;                 // 2*1024*256 fp32 (MFMA-A-frag tiled)
    float* Qcq   = ws + 524288;        // 200*256
    float* gpart = ws + 575488;        // 512*128
    float* ppart = ws + 641024;        // 512
    short* W2T   = (short*)(ws + 641536);  // 128*256 bf16, MFMA-B-frag tiled
    float* Gterm = ws + 657920;        // 2*256

    kA_fused<<<744, 256, 0, stream>>>(x, ln_g, ln_b, W_in, b_in, policy,
                                      query, W1, W2, At, Qcq, gpart, ppart, W2T);
    kB_gterm<<<BB, 256, 0, stream>>>(W1, gpart, ppart, b1, Gterm);
    k5_main<<<1600, 256, 0, stream>>>(At, Qcq, Gterm, W2T, b2, W3, b3, out);
}

// Round 13
// 151.530 us; speedup vs baseline: 2.0485x; 1.0142x over previous
//
#include <hip/hip_runtime.h>
#include <hip/hip_bf16.h>
#include <math.h>

#define BB 2
#define NN 1024
#define CC 256
#define NQ 100
#define HALF 128

typedef __attribute__((ext_vector_type(8))) short bf16x8;
typedef __attribute__((ext_vector_type(4))) float f32x4;

__device__ __forceinline__ float exp2_fast(float v) {
#if __has_builtin(__builtin_amdgcn_exp2f)
    return __builtin_amdgcn_exp2f(v);
#else
    return __expf(0.69314718056f * v);
#endif
}

// gelu tanh-form: x * sigmoid(2*c1*(x + c2*x^3)); |err vs erf-gelu| <= ~3e-4.
__device__ __forceinline__ float gelu_fast(float x) {
    float x2 = x * x;
    float v = x * fmaf(0.10293942f, x2, 2.30211418f);
    float e = exp2_fast(v);
    float r = __builtin_amdgcn_rcpf(1.0f + e);
    return fmaf(-x, r, x);
}

__device__ __forceinline__ short f2bf(float f) {
    union { float f; unsigned u; } v; v.f = f;
    return (short)((v.u + 0x7FFFu + ((v.u >> 16) & 1u)) >> 16);
}

// ---- kA: all independent producers in one dispatch.
//   blocks 0..511:   LN -> W_in GEMM -> gelu -> gpart/ppart; h@W1lo -> At tiled
//   blocks 512..711: Qcq[row] = q[b,i] @ W1[256:512]
//   blocks 712..743: W2 -> bf16 MFMA-B-frag tiled W2T
// At layout: At[((b*64 + row/16)*32 + k/8)*128 + (row%16)*8 + k%8].
__global__ __launch_bounds__(256) void kA_fused(
        const float* __restrict__ x, const float* __restrict__ ln_g,
        const float* __restrict__ ln_b, const float* __restrict__ W_in,
        const float* __restrict__ b_in, const float* __restrict__ policy,
        const float* __restrict__ query, const float* __restrict__ W1,
        const float* __restrict__ W2, float* __restrict__ At,
        float* __restrict__ Qcq, float* __restrict__ gpart,
        float* __restrict__ ppart, short* __restrict__ W2T) {
    __shared__ float xst[CC][4];
    __shared__ float hst[HALF][4];
    int t = threadIdx.x;
    int blk = blockIdx.x;
    if (blk >= 712) {
        // W2 -> bf16 MFMA-B-frag tiling (coalesced reads)
        int u = (blk - 712) * 256 + t;
        int n = u & 127;
        int kq = u >> 7;
        short4 v;
        v.x = f2bf(W2[(kq * 4 + 0) * HALF + n]);
        v.y = f2bf(W2[(kq * 4 + 1) * HALF + n]);
        v.z = f2bf(W2[(kq * 4 + 2) * HALF + n]);
        v.w = f2bf(W2[(kq * 4 + 3) * HALF + n]);
        *(short4*)(W2T + (size_t)((n >> 4) * 32 + (kq >> 1)) * 128
                   + (n & 15) * 8 + (kq & 1) * 4) = v;
        return;
    }
    if (blk >= 512) {
        // Qcq = q @ W1[256:512]
        float* qs = (float*)xst;
        int row = blk - 512;
        int b = row / NQ, i = row % NQ;
        qs[t] = query[(size_t)(i * BB + b) * CC + t];
        __syncthreads();
        float g = 0.f;
        #pragma unroll 8
        for (int k = 0; k < CC; ++k)
            g = fmaf(qs[k], W1[(2 * HALF + k) * CC + t], g);
        Qcq[(size_t)row * CC + t] = g;
        return;
    }
    int wave = t >> 6, lane = t & 63;
    int row0 = blk * 4;
    const float* xr = x + (size_t)(row0 + wave) * CC;
    float v0 = xr[lane], v1 = xr[lane + 64], v2 = xr[lane + 128], v3 = xr[lane + 192];
    float s = v0 + v1 + v2 + v3;
    for (int off = 32; off; off >>= 1) s += __shfl_down(s, off);
    s = __shfl(s, 0);
    float mu = s * (1.0f / CC);
    float d0 = v0 - mu, d1 = v1 - mu, d2 = v2 - mu, d3 = v3 - mu;
    float vs = d0 * d0 + d1 * d1 + d2 * d2 + d3 * d3;
    for (int off = 32; off; off >>= 1) vs += __shfl_down(vs, off);
    vs = __shfl(vs, 0);
    float rstd = rsqrtf(vs * (1.0f / CC) + 1e-5f);
    xst[lane][wave]       = d0 * rstd * ln_g[lane]       + ln_b[lane];
    xst[lane + 64][wave]  = d1 * rstd * ln_g[lane + 64]  + ln_b[lane + 64];
    xst[lane + 128][wave] = d2 * rstd * ln_g[lane + 128] + ln_b[lane + 128];
    xst[lane + 192][wave] = d3 * rstd * ln_g[lane + 192] + ln_b[lane + 192];
    __syncthreads();
    float a0 = b_in[t], a1 = a0, a2 = a0, a3 = a0;
    #pragma unroll 8
    for (int k = 0; k < CC; ++k) {
        float4 xv = *(const float4*)xst[k];     // uniform addr -> broadcast
        float wv = W_in[k * CC + t];
        a0 = fmaf(xv.x, wv, a0); a1 = fmaf(xv.y, wv, a1);
        a2 = fmaf(xv.z, wv, a2); a3 = fmaf(xv.w, wv, a3);
    }
    float h0 = gelu_fast(a0), h1 = gelu_fast(a1);
    float h2 = gelu_fast(a2), h3 = gelu_fast(a3);
    float p0 = policy[row0], p1 = policy[row0 + 1];
    float p2 = policy[row0 + 2], p3 = policy[row0 + 3];
    if (t < HALF) {
        hst[t][0] = h0; hst[t][1] = h1; hst[t][2] = h2; hst[t][3] = h3;
    } else {
        gpart[(size_t)blk * HALF + (t - HALF)] =
            h0 * p0 + h1 * p1 + h2 * p2 + h3 * p3;
    }
    if (t == 0) ppart[blk] = p0 + p1 + p2 + p3;
    __syncthreads();
    float c0 = 0, c1 = 0, c2 = 0, c3 = 0;
    #pragma unroll 8
    for (int k = 0; k < HALF; ++k) {
        float4 hv = *(const float4*)hst[k];     // uniform addr -> broadcast
        float wv = W1[k * CC + t];
        c0 = fmaf(hv.x, wv, c0); c1 = fmaf(hv.y, wv, c1);
        c2 = fmaf(hv.z, wv, c2); c3 = fmaf(hv.w, wv, c3);
    }
    int b = row0 >> 10;
    int lr = row0 & (NN - 1);
    size_t tb = ((size_t)(b * 64 + (lr >> 4)) * 32 + (t >> 3)) * 128 + (t & 7);
    int r16 = lr & 15;
    At[tb + (r16 + 0) * 8] = c0;
    At[tb + (r16 + 1) * 8] = c1;
    At[tb + (r16 + 2) * 8] = c2;
    At[tb + (r16 + 3) * 8] = c3;
}

// ---- kB: 2 blocks. glob = (Σ gpart)/(Σ ppart); Gterm[b] = b1 + glob@W1mid. ----
__global__ __launch_bounds__(256) void kB_gterm(
        const float* __restrict__ W1, const float* __restrict__ gpart,
        const float* __restrict__ ppart, const float* __restrict__ b1,
        float* __restrict__ Gterm) {
    __shared__ float gl2[2][HALF];
    __shared__ float gls[HALF];
    __shared__ float pss;
    int b = blockIdx.x, t = threadIdx.x;
    int c = t & 127, hh = t >> 7;
    {
        const float* gp = gpart + ((size_t)b * 256 + hh * 128) * HALF + c;
        float s = 0.f;
        #pragma unroll 16
        for (int ch = 0; ch < 128; ++ch) s += gp[(size_t)ch * HALF];
        gl2[hh][c] = s;
    }
    if (t < 64) {
        const float* pp = ppart + b * 256;
        float ps = pp[t] + pp[t + 64] + pp[t + 128] + pp[t + 192];
        for (int off = 32; off; off >>= 1) ps += __shfl_down(ps, off);
        if (t == 0) pss = ps;
    }
    __syncthreads();
    if (t < HALF) gls[t] = (gl2[0][t] + gl2[1][t]) / pss;
    __syncthreads();
    float g = b1[t];
    #pragma unroll 8
    for (int k = 0; k < HALF; ++k)
        g = fmaf(gls[k], W1[(HALF + k) * CC + t], g);
    Gterm[b * CC + t] = g;
}

// ---- k5: block tile M=128 x N=128; 4 waves, wave-tile m=32 x n=128 (acc 64).
// z1 = gelu(At + Qcq + Gterm) in-register; W2 per-32k chunk in frag-tiled dbuf
// LDS (conflict-free, 8 DS-reads serve 16 MFMAs); single 1600-block dispatch. ----
__global__ __launch_bounds__(256, 4) void k5_main(
        const float* __restrict__ At, const float* __restrict__ Qcq,
        const float* __restrict__ Gterm, const short* __restrict__ W2T,
        const float* __restrict__ b2, const float* __restrict__ W3,
        const float* __restrict__ b3, float* __restrict__ out) {
    __shared__ short w2s[2][4096];   // 2 x 8 KB

    int t = threadIdx.x;
    int lane = t & 63, w = t >> 6;
    int col16 = lane & 15, quad = lane >> 4;
    int blk = blockIdx.x;                // 0..1599
    int jt = blk & 7;                    // 8 j-tiles of 128 rows
    int iq = (blk >> 3) % NQ;
    int b  = blk / (8 * NQ);
    const float* A0 = At + (size_t)(b * 64 + jt * 8 + w * 2) * 4096 + col16 * 8;
    const float* Qrow = Qcq + (size_t)(b * NQ + iq) * CC;
    const float* Grow = Gterm + b * CC;
    const short* Wg = W2T + (size_t)((t >> 6) * 32 + ((t >> 4) & 3)) * 128
                      + (t & 15) * 8;

    f32x4 acc[2][8];
    #pragma unroll
    for (int mi = 0; mi < 2; ++mi)
        #pragma unroll
        for (int ni = 0; ni < 8; ++ni)
            acc[mi][ni] = (f32x4){0.f, 0.f, 0.f, 0.f};

    // prologue: chunk0 -> buf0; chunk1 -> regs; A/Q/G(kt=0) -> regs
    bf16x8 nx0 = *(const bf16x8*)(Wg);
    bf16x8 nx1 = *(const bf16x8*)(Wg + 16384);
    float4 a00 = *(const float4*)(A0 + quad * 128);
    float4 a01 = *(const float4*)(A0 + quad * 128 + 4);
    float4 a10 = *(const float4*)(A0 + 4096 + quad * 128);
    float4 a11 = *(const float4*)(A0 + 4096 + quad * 128 + 4);
    float4 q0 = *(const float4*)(Qrow + quad * 8);
    float4 q1 = *(const float4*)(Qrow + quad * 8 + 4);
    float4 g0 = *(const float4*)(Grow + quad * 8);
    float4 g1 = *(const float4*)(Grow + quad * 8 + 4);
    *(bf16x8*)&w2s[0][t * 8] = nx0;
    *(bf16x8*)&w2s[0][2048 + t * 8] = nx1;
    nx0 = *(const bf16x8*)(Wg + 512);
    nx1 = *(const bf16x8*)(Wg + 16384 + 512);
    __syncthreads();

    #pragma unroll
    for (int kt = 0; kt < 8; ++kt) {
        int buf = kt & 1;
        if (kt < 7) {
            *(bf16x8*)&w2s[1 - buf][t * 8] = nx0;
            *(bf16x8*)&w2s[1 - buf][2048 + t * 8] = nx1;
        }
        if (kt < 6) {
            nx0 = *(const bf16x8*)(Wg + (kt + 2) * 512);
            nx1 = *(const bf16x8*)(Wg + 16384 + (kt + 2) * 512);
        }
        float qg0x = q0.x + g0.x, qg0y = q0.y + g0.y;
        float qg0z = q0.z + g0.z, qg0w = q0.w + g0.w;
        float qg1x = q1.x + g1.x, qg1y = q1.y + g1.y;
        float qg1z = q1.z + g1.z, qg1w = q1.w + g1.w;
        union { bf16x8 v; __hip_bfloat162 h[4]; } f0, f1;
        f0.h[0] = __float22bfloat162_rn(make_float2(gelu_fast(a00.x + qg0x),
                                                   gelu_fast(a00.y + qg0y)));
        f0.h[1] = __float22bfloat162_rn(make_float2(gelu_fast(a00.z + qg0z),
                                                   gelu_fast(a00.w + qg0w)));
        f0.h[2] = __float22bfloat162_rn(make_float2(gelu_fast(a01.x + qg1x),
                                                   gelu_fast(a01.y + qg1y)));
        f0.h[3] = __float22bfloat162_rn(make_float2(gelu_fast(a01.z + qg1z),
                                                   gelu_fast(a01.w + qg1w)));
        f1.h[0] = __float22bfloat162_rn(make_float2(gelu_fast(a10.x + qg0x),
                                                   gelu_fast(a10.y + qg0y)));
        f1.h[1] = __float22bfloat162_rn(make_float2(gelu_fast(a10.z + qg0z),
                                                   gelu_fast(a10.w + qg0w)));
        f1.h[2] = __float22bfloat162_rn(make_float2(gelu_fast(a11.x + qg1x),
                                                   gelu_fast(a11.y + qg1y)));
        f1.h[3] = __float22bfloat162_rn(make_float2(gelu_fast(a11.z + qg1z),
                                                   gelu_fast(a11.w + qg1w)));
        if (kt < 7) {
            const float* Ap = A0 + (size_t)((kt + 1) * 4 + quad) * 128;
            a00 = *(const float4*)(Ap);
            a01 = *(const float4*)(Ap + 4);
            a10 = *(const float4*)(Ap + 4096);
            a11 = *(const float4*)(Ap + 4096 + 4);
            q0 = *(const float4*)(Qrow + (kt + 1) * 32 + quad * 8);
            q1 = *(const float4*)(Qrow + (kt + 1) * 32 + quad * 8 + 4);
            g0 = *(const float4*)(Grow + (kt + 1) * 32 + quad * 8);
            g1 = *(const float4*)(Grow + (kt + 1) * 32 + quad * 8 + 4);
        }
        #pragma unroll
        for (int ni = 0; ni < 8; ++ni) {
            bf16x8 bv = *(const bf16x8*)&w2s[buf][(ni * 64 + lane) * 8];
            acc[0][ni] = __builtin_amdgcn_mfma_f32_16x16x32_bf16(f0.v, bv,
                                                                 acc[0][ni], 0, 0, 0);
            acc[1][ni] = __builtin_amdgcn_mfma_f32_16x16x32_bf16(f1.v, bv,
                                                                 acc[1][ni], 0, 0, 0);
        }
        if (kt < 7) __syncthreads();
    }

    // epilogue: z2 = gelu(acc + b2); logits = z2@W3; reduce over col16; lsm
    float b30 = b3[0], b31 = b3[1];
    #pragma unroll
    for (int mi = 0; mi < 2; ++mi) {
        float p0[4] = {0, 0, 0, 0}, p1[4] = {0, 0, 0, 0};
        #pragma unroll
        for (int ni = 0; ni < 8; ++ni) {
            int c = ni * 16 + col16;
            float bb = b2[c];
            float2 w3v = *(const float2*)(W3 + c * 2);
            #pragma unroll
            for (int r = 0; r < 4; ++r) {
                float z = gelu_fast(acc[mi][ni][r] + bb);
                p0[r] = fmaf(z, w3v.x, p0[r]);
                p1[r] = fmaf(z, w3v.y, p1[r]);
            }
        }
        #pragma unroll
        for (int r = 0; r < 4; ++r) {
            float s0 = p0[r], s1 = p1[r];
            #pragma unroll
            for (int off = 1; off < 16; off <<= 1) {
                s0 += __shfl_xor(s0, off);
                s1 += __shfl_xor(s1, off);
            }
            if (col16 == 0) {
                float z0 = s0 + b30, z1v = s1 + b31;
                float m = fmaxf(z0, z1v);
                float lse = m + __logf(__expf(z0 - m) + __expf(z1v - m));
                int j = jt * 128 + w * 32 + mi * 16 + quad * 4 + r;
                *(float2*)(out + ((size_t)(b * NQ + iq) * NN + j) * 2) =
                    make_float2(z0 - lse, z1v - lse);
            }
        }
    }
}

extern "C" void kernel_launch(void* const* d_in, const int* in_sizes, int n_in,
                              void* d_out, int out_size, void* d_ws, size_t ws_size,
                              hipStream_t stream) {
    const float* x      = (const float*)d_in[0];
    const float* query  = (const float*)d_in[1];
    const float* policy = (const float*)d_in[2];
    const float* ln_g   = (const float*)d_in[3];
    const float* ln_b   = (const float*)d_in[4];
    const float* W_in   = (const float*)d_in[5];
    const float* b_in   = (const float*)d_in[6];
    const float* W1     = (const float*)d_in[7];
    const float* b1     = (const float*)d_in[8];
    const float* W2     = (const float*)d_in[9];
    const float* b2     = (const float*)d_in[10];
    const float* W3     = (const float*)d_in[11];
    const float* b3     = (const float*)d_in[12];
    float* out = (float*)d_out;

    float* ws    = (float*)d_ws;
    float* At    = ws;                 // 2*1024*256 fp32 (MFMA-A-frag tiled)
    float* Qcq   = ws + 524288;        // 200*256
    float* gpart = ws + 575488;        // 512*128
    float* ppart = ws + 641024;        // 512
    short* W2T   = (short*)(ws + 641536);  // 128*256 bf16, MFMA-B-frag tiled
    float* Gterm = ws + 657920;        // 2*256

    kA_fused<<<744, 256, 0, stream>>>(x, ln_g, ln_b, W_in, b_in, policy,
                                      query, W1, W2, At, Qcq, gpart, ppart, W2T);
    kB_gterm<<<BB, 256, 0, stream>>>(W1, gpart, ppart, b1, Gterm);
    k5_main<<<1600, 256, 0, stream>>>(At, Qcq, Gterm, W2T, b2, W3, b3, out);
}

// Round 14
// 142.383 us; speedup vs baseline: 2.1801x; 1.0642x over previous
//
#include <hip/hip_runtime.h>
#include <hip/hip_bf16.h>
#include <math.h>

#define BB 2
#define NN 1024
#define CC 256
#define NQ 100
#define HALF 128

typedef __attribute__((ext_vector_type(8))) short bf16x8;
typedef __attribute__((ext_vector_type(4))) float f32x4;

__device__ __forceinline__ float exp2_fast(float v) {
#if __has_builtin(__builtin_amdgcn_exp2f)
    return __builtin_amdgcn_exp2f(v);
#else
    return __expf(0.69314718056f * v);
#endif
}

// gelu tanh-form: x * sigmoid(2*c1*(x + c2*x^3)); |err vs erf-gelu| <= ~3e-4.
__device__ __forceinline__ float gelu_fast(float x) {
    float x2 = x * x;
    float v = x * fmaf(0.10293942f, x2, 2.30211418f);
    float e = exp2_fast(v);
    float r = __builtin_amdgcn_rcpf(1.0f + e);
    return fmaf(-x, r, x);
}

__device__ __forceinline__ short f2bf(float f) {
    union { float f; unsigned u; } v; v.f = f;
    return (short)((v.u + 0x7FFFu + ((v.u >> 16) & 1u)) >> 16);
}

// ---- kA: all independent producers in one dispatch (r13-proven).
//   blocks 0..511:   LN -> W_in GEMM -> gelu -> gpart/ppart; h@W1lo -> At tiled
//   blocks 512..711: Qcq[row] = q[b,i] @ W1[256:512]
//   blocks 712..743: W2 -> bf16 MFMA-B-frag tiled W2T
// At layout: At[((b*64 + row/16)*32 + k/8)*128 + (row%16)*8 + k%8].
__global__ __launch_bounds__(256) void kA_fused(
        const float* __restrict__ x, const float* __restrict__ ln_g,
        const float* __restrict__ ln_b, const float* __restrict__ W_in,
        const float* __restrict__ b_in, const float* __restrict__ policy,
        const float* __restrict__ query, const float* __restrict__ W1,
        const float* __restrict__ W2, float* __restrict__ At,
        float* __restrict__ Qcq, float* __restrict__ gpart,
        float* __restrict__ ppart, short* __restrict__ W2T) {
    __shared__ float xst[CC][4];
    __shared__ float hst[HALF][4];
    int t = threadIdx.x;
    int blk = blockIdx.x;
    if (blk >= 712) {
        int u = (blk - 712) * 256 + t;
        int n = u & 127;
        int kq = u >> 7;
        short4 v;
        v.x = f2bf(W2[(kq * 4 + 0) * HALF + n]);
        v.y = f2bf(W2[(kq * 4 + 1) * HALF + n]);
        v.z = f2bf(W2[(kq * 4 + 2) * HALF + n]);
        v.w = f2bf(W2[(kq * 4 + 3) * HALF + n]);
        *(short4*)(W2T + (size_t)((n >> 4) * 32 + (kq >> 1)) * 128
                   + (n & 15) * 8 + (kq & 1) * 4) = v;
        return;
    }
    if (blk >= 512) {
        float* qs = (float*)xst;
        int row = blk - 512;
        int b = row / NQ, i = row % NQ;
        qs[t] = query[(size_t)(i * BB + b) * CC + t];
        __syncthreads();
        float g = 0.f;
        #pragma unroll 8
        for (int k = 0; k < CC; ++k)
            g = fmaf(qs[k], W1[(2 * HALF + k) * CC + t], g);
        Qcq[(size_t)row * CC + t] = g;
        return;
    }
    int wave = t >> 6, lane = t & 63;
    int row0 = blk * 4;
    const float* xr = x + (size_t)(row0 + wave) * CC;
    float v0 = xr[lane], v1 = xr[lane + 64], v2 = xr[lane + 128], v3 = xr[lane + 192];
    float s = v0 + v1 + v2 + v3;
    for (int off = 32; off; off >>= 1) s += __shfl_down(s, off);
    s = __shfl(s, 0);
    float mu = s * (1.0f / CC);
    float d0 = v0 - mu, d1 = v1 - mu, d2 = v2 - mu, d3 = v3 - mu;
    float vs = d0 * d0 + d1 * d1 + d2 * d2 + d3 * d3;
    for (int off = 32; off; off >>= 1) vs += __shfl_down(vs, off);
    vs = __shfl(vs, 0);
    float rstd = rsqrtf(vs * (1.0f / CC) + 1e-5f);
    xst[lane][wave]       = d0 * rstd * ln_g[lane]       + ln_b[lane];
    xst[lane + 64][wave]  = d1 * rstd * ln_g[lane + 64]  + ln_b[lane + 64];
    xst[lane + 128][wave] = d2 * rstd * ln_g[lane + 128] + ln_b[lane + 128];
    xst[lane + 192][wave] = d3 * rstd * ln_g[lane + 192] + ln_b[lane + 192];
    __syncthreads();
    float a0 = b_in[t], a1 = a0, a2 = a0, a3 = a0;
    #pragma unroll 8
    for (int k = 0; k < CC; ++k) {
        float4 xv = *(const float4*)xst[k];     // uniform addr -> broadcast
        float wv = W_in[k * CC + t];
        a0 = fmaf(xv.x, wv, a0); a1 = fmaf(xv.y, wv, a1);
        a2 = fmaf(xv.z, wv, a2); a3 = fmaf(xv.w, wv, a3);
    }
    float h0 = gelu_fast(a0), h1 = gelu_fast(a1);
    float h2 = gelu_fast(a2), h3 = gelu_fast(a3);
    float p0 = policy[row0], p1 = policy[row0 + 1];
    float p2 = policy[row0 + 2], p3 = policy[row0 + 3];
    if (t < HALF) {
        hst[t][0] = h0; hst[t][1] = h1; hst[t][2] = h2; hst[t][3] = h3;
    } else {
        gpart[(size_t)blk * HALF + (t - HALF)] =
            h0 * p0 + h1 * p1 + h2 * p2 + h3 * p3;
    }
    if (t == 0) ppart[blk] = p0 + p1 + p2 + p3;
    __syncthreads();
    float c0 = 0, c1 = 0, c2 = 0, c3 = 0;
    #pragma unroll 8
    for (int k = 0; k < HALF; ++k) {
        float4 hv = *(const float4*)hst[k];     // uniform addr -> broadcast
        float wv = W1[k * CC + t];
        c0 = fmaf(hv.x, wv, c0); c1 = fmaf(hv.y, wv, c1);
        c2 = fmaf(hv.z, wv, c2); c3 = fmaf(hv.w, wv, c3);
    }
    int b = row0 >> 10;
    int lr = row0 & (NN - 1);
    size_t tb = ((size_t)(b * 64 + (lr >> 4)) * 32 + (t >> 3)) * 128 + (t & 7);
    int r16 = lr & 15;
    At[tb + (r16 + 0) * 8] = c0;
    At[tb + (r16 + 1) * 8] = c1;
    At[tb + (r16 + 2) * 8] = c2;
    At[tb + (r16 + 3) * 8] = c3;
}

// ---- kB: 200 blocks. Each redundantly reduces gpart/ppart for its b (L2-hot),
//      then Qc[row] = Qcq[row] + b1 + glob@W1[128:256]  (r7-proven pattern). ----
__global__ __launch_bounds__(256) void kB_combine(
        const float* __restrict__ W1, const float* __restrict__ gpart,
        const float* __restrict__ ppart, const float* __restrict__ b1,
        const float* __restrict__ Qcq, float* __restrict__ Qc) {
    __shared__ float gl2[2][HALF];
    __shared__ float gls[HALF];
    __shared__ float pss;
    int blk = blockIdx.x, t = threadIdx.x;
    int b = blk / NQ;
    int c = t & 127, hh = t >> 7;
    {
        const float* gp = gpart + ((size_t)b * 256 + hh * 128) * HALF + c;
        float s = 0.f;
        #pragma unroll 16
        for (int ch = 0; ch < 128; ++ch) s += gp[(size_t)ch * HALF];
        gl2[hh][c] = s;
    }
    if (t < 64) {
        const float* pp = ppart + b * 256;
        float ps = pp[t] + pp[t + 64] + pp[t + 128] + pp[t + 192];
        for (int off = 32; off; off >>= 1) ps += __shfl_down(ps, off);
        if (t == 0) pss = ps;
    }
    __syncthreads();
    if (t < HALF) gls[t] = (gl2[0][t] + gl2[1][t]) / pss;
    __syncthreads();
    float g = b1[t] + Qcq[(size_t)blk * CC + t];
    #pragma unroll 8
    for (int k = 0; k < HALF; ++k)
        g = fmaf(gls[k], W1[(HALF + k) * CC + t], g);
    Qc[(size_t)blk * CC + t] = g;
}

// ---- k5: r7-proven structure. Block M=64 x N=128; 4 waves, wave-tile 16x128
// (acc 32 AGPR). z1 = gelu(At + Qc) in-register; W2 per-32k chunk in frag-tiled
// dbuf LDS (conflict-free); 3200 blocks, single dispatch. ----
__global__ __launch_bounds__(256, 4) void k5_main(
        const float* __restrict__ At, const float* __restrict__ Qc,
        const short* __restrict__ W2T, const float* __restrict__ b2,
        const float* __restrict__ W3, const float* __restrict__ b3,
        float* __restrict__ out) {
    __shared__ short w2s[2][4096];   // 2 x 8 KB

    int t = threadIdx.x;
    int lane = t & 63, w = t >> 6;
    int col16 = lane & 15, quad = lane >> 4;
    int blk = blockIdx.x;                // 0..3199
    int jt = blk & 15;                   // 16 j-tiles of 64 rows
    int iq = (blk >> 4) % NQ;
    int b  = blk / (16 * NQ);
    const float* Abase = At + ((size_t)(b * 64 + jt * 4 + w) * 32) * 128 + col16 * 8;
    const float* Qrow = Qc + (size_t)(b * NQ + iq) * CC;
    const short* Wg = W2T + (size_t)((t >> 6) * 32 + ((t >> 4) & 3)) * 128
                      + (t & 15) * 8;

    f32x4 acc[8];
    #pragma unroll
    for (int ni = 0; ni < 8; ++ni) acc[ni] = (f32x4){0.f, 0.f, 0.f, 0.f};

    // prologue: chunk0 -> buf0; chunk1 -> regs; A/Q(kt=0) -> regs
    bf16x8 nx0 = *(const bf16x8*)(Wg);
    bf16x8 nx1 = *(const bf16x8*)(Wg + 16384);
    float4 a0 = *(const float4*)(Abase + quad * 128);
    float4 a1 = *(const float4*)(Abase + quad * 128 + 4);
    float4 q0 = *(const float4*)(Qrow + quad * 8);
    float4 q1 = *(const float4*)(Qrow + quad * 8 + 4);
    *(bf16x8*)&w2s[0][t * 8] = nx0;
    *(bf16x8*)&w2s[0][2048 + t * 8] = nx1;
    nx0 = *(const bf16x8*)(Wg + 512);
    nx1 = *(const bf16x8*)(Wg + 16384 + 512);
    __syncthreads();

    #pragma unroll
    for (int kt = 0; kt < 8; ++kt) {
        int buf = kt & 1;
        if (kt < 7) {
            *(bf16x8*)&w2s[1 - buf][t * 8] = nx0;
            *(bf16x8*)&w2s[1 - buf][2048 + t * 8] = nx1;
        }
        if (kt < 6) {
            nx0 = *(const bf16x8*)(Wg + (kt + 2) * 512);
            nx1 = *(const bf16x8*)(Wg + 16384 + (kt + 2) * 512);
        }
        union { bf16x8 v; __hip_bfloat162 h[4]; } fr;
        fr.h[0] = __float22bfloat162_rn(make_float2(gelu_fast(a0.x + q0.x),
                                                   gelu_fast(a0.y + q0.y)));
        fr.h[1] = __float22bfloat162_rn(make_float2(gelu_fast(a0.z + q0.z),
                                                   gelu_fast(a0.w + q0.w)));
        fr.h[2] = __float22bfloat162_rn(make_float2(gelu_fast(a1.x + q1.x),
                                                   gelu_fast(a1.y + q1.y)));
        fr.h[3] = __float22bfloat162_rn(make_float2(gelu_fast(a1.z + q1.z),
                                                   gelu_fast(a1.w + q1.w)));
        if (kt < 7) {
            const float* Ap = Abase + (size_t)((kt + 1) * 4 + quad) * 128;
            a0 = *(const float4*)(Ap);
            a1 = *(const float4*)(Ap + 4);
            q0 = *(const float4*)(Qrow + (kt + 1) * 32 + quad * 8);
            q1 = *(const float4*)(Qrow + (kt + 1) * 32 + quad * 8 + 4);
        }
        #pragma unroll
        for (int ni = 0; ni < 8; ++ni) {
            bf16x8 bv = *(const bf16x8*)&w2s[buf][(ni * 64 + lane) * 8];
            acc[ni] = __builtin_amdgcn_mfma_f32_16x16x32_bf16(fr.v, bv,
                                                              acc[ni], 0, 0, 0);
        }
        if (kt < 7) __syncthreads();
    }

    // epilogue: z2 = gelu(acc + b2); logits = z2@W3; reduce over col16; lsm
    float p0[4] = {0, 0, 0, 0}, p1[4] = {0, 0, 0, 0};
    #pragma unroll
    for (int ni = 0; ni < 8; ++ni) {
        int c = ni * 16 + col16;
        float bb = b2[c];
        float2 w3v = *(const float2*)(W3 + c * 2);
        #pragma unroll
        for (int r = 0; r < 4; ++r) {
            float z = gelu_fast(acc[ni][r] + bb);
            p0[r] = fmaf(z, w3v.x, p0[r]);
            p1[r] = fmaf(z, w3v.y, p1[r]);
        }
    }
    float b30 = b3[0], b31 = b3[1];
    #pragma unroll
    for (int r = 0; r < 4; ++r) {
        float s0 = p0[r], s1 = p1[r];
        #pragma unroll
        for (int off = 1; off < 16; off <<= 1) {
            s0 += __shfl_xor(s0, off);
            s1 += __shfl_xor(s1, off);
        }
        if (col16 == 0) {
            float z0 = s0 + b30, z1v = s1 + b31;
            float m = fmaxf(z0, z1v);
            float lse = m + __logf(__expf(z0 - m) + __expf(z1v - m));
            int j = jt * 64 + w * 16 + quad * 4 + r;
            *(float2*)(out + ((size_t)(b * NQ + iq) * NN + j) * 2) =
                make_float2(z0 - lse, z1v - lse);
        }
    }
}

extern "C" void kernel_launch(void* const* d_in, const int* in_sizes, int n_in,
                              void* d_out, int out_size, void* d_ws, size_t ws_size,
                              hipStream_t stream) {
    const float* x      = (const float*)d_in[0];
    const float* query  = (const float*)d_in[1];
    const float* policy = (const float*)d_in[2];
    const float* ln_g   = (const float*)d_in[3];
    const float* ln_b   = (const float*)d_in[4];
    const float* W_in   = (const float*)d_in[5];
    const float* b_in   = (const float*)d_in[6];
    const float* W1     = (const float*)d_in[7];
    const float* b1     = (const float*)d_in[8];
    const float* W2     = (const float*)d_in[9];
    const float* b2     = (const float*)d_in[10];
    const float* W3     = (const float*)d_in[11];
    const float* b3     = (const float*)d_in[12];
    float* out = (float*)d_out;

    float* ws    = (float*)d_ws;
    float* At    = ws;                 // 524288 fp32 (MFMA-A-frag tiled)
    float* Qcq   = ws + 524288;        // 200*256
    float* Qc    = ws + 575488;        // 200*256 (combined)
    float* gpart = ws + 626688;        // 512*128
    float* ppart = ws + 692224;        // 512
    short* W2T   = (short*)(ws + 692736);  // 128*256 bf16, MFMA-B-frag tiled

    kA_fused<<<744, 256, 0, stream>>>(x, ln_g, ln_b, W_in, b_in, policy,
                                      query, W1, W2, At, Qcq, gpart, ppart, W2T);
    kB_combine<<<BB * NQ, 256, 0, stream>>>(W1, gpart, ppart, b1, Qcq, Qc);
    k5_main<<<3200, 256, 0, stream>>>(At, Qc, W2T, b2, W3, b3, out);
}

// Round 15
// 141.492 us; speedup vs baseline: 2.1938x; 1.0063x over previous
//
#include <hip/hip_runtime.h>
#include <hip/hip_bf16.h>
#include <math.h>

#define BB 2
#define NN 1024
#define CC 256
#define NQ 100
#define HALF 128

typedef __attribute__((ext_vector_type(8))) short bf16x8;
typedef __attribute__((ext_vector_type(4))) float f32x4;

__device__ __forceinline__ float exp2_fast(float v) {
#if __has_builtin(__builtin_amdgcn_exp2f)
    return __builtin_amdgcn_exp2f(v);
#else
    return __expf(0.69314718056f * v);
#endif
}

// gelu tanh-form: x * sigmoid(2*c1*(x + c2*x^3)); |err vs erf-gelu| <= ~3e-4.
__device__ __forceinline__ float gelu_fast(float x) {
    float x2 = x * x;
    float v = x * fmaf(0.10293942f, x2, 2.30211418f);
    float e = exp2_fast(v);
    float r = __builtin_amdgcn_rcpf(1.0f + e);
    return fmaf(-x, r, x);
}

__device__ __forceinline__ short f2bf(float f) {
    union { float f; unsigned u; } v; v.f = f;
    return (short)((v.u + 0x7FFFu + ((v.u >> 16) & 1u)) >> 16);
}

// ---- kA: all independent producers in one dispatch (r13/r14-proven).
//   blocks 0..511:   LN -> W_in GEMM -> gelu -> gpart/ppart; h@W1lo -> At tiled
//   blocks 512..711: Qcq[row] = q[b,i] @ W1[256:512]
//   blocks 712..743: W2 -> bf16 MFMA-B-frag tiled W2T
// At layout: At[((b*64 + row/16)*32 + k/8)*128 + (row%16)*8 + k%8].
__global__ __launch_bounds__(256) void kA_fused(
        const float* __restrict__ x, const float* __restrict__ ln_g,
        const float* __restrict__ ln_b, const float* __restrict__ W_in,
        const float* __restrict__ b_in, const float* __restrict__ policy,
        const float* __restrict__ query, const float* __restrict__ W1,
        const float* __restrict__ W2, float* __restrict__ At,
        float* __restrict__ Qcq, float* __restrict__ gpart,
        float* __restrict__ ppart, short* __restrict__ W2T) {
    __shared__ float xst[CC][4];
    __shared__ float hst[HALF][4];
    int t = threadIdx.x;
    int blk = blockIdx.x;
    if (blk >= 712) {
        int u = (blk - 712) * 256 + t;
        int n = u & 127;
        int kq = u >> 7;
        short4 v;
        v.x = f2bf(W2[(kq * 4 + 0) * HALF + n]);
        v.y = f2bf(W2[(kq * 4 + 1) * HALF + n]);
        v.z = f2bf(W2[(kq * 4 + 2) * HALF + n]);
        v.w = f2bf(W2[(kq * 4 + 3) * HALF + n]);
        *(short4*)(W2T + (size_t)((n >> 4) * 32 + (kq >> 1)) * 128
                   + (n & 15) * 8 + (kq & 1) * 4) = v;
        return;
    }
    if (blk >= 512) {
        float* qs = (float*)xst;
        int row = blk - 512;
        int b = row / NQ, i = row % NQ;
        qs[t] = query[(size_t)(i * BB + b) * CC + t];
        __syncthreads();
        float g = 0.f;
        #pragma unroll 8
        for (int k = 0; k < CC; ++k)
            g = fmaf(qs[k], W1[(2 * HALF + k) * CC + t], g);
        Qcq[(size_t)row * CC + t] = g;
        return;
    }
    int wave = t >> 6, lane = t & 63;
    int row0 = blk * 4;
    const float* xr = x + (size_t)(row0 + wave) * CC;
    float v0 = xr[lane], v1 = xr[lane + 64], v2 = xr[lane + 128], v3 = xr[lane + 192];
    float s = v0 + v1 + v2 + v3;
    for (int off = 32; off; off >>= 1) s += __shfl_down(s, off);
    s = __shfl(s, 0);
    float mu = s * (1.0f / CC);
    float d0 = v0 - mu, d1 = v1 - mu, d2 = v2 - mu, d3 = v3 - mu;
    float vs = d0 * d0 + d1 * d1 + d2 * d2 + d3 * d3;
    for (int off = 32; off; off >>= 1) vs += __shfl_down(vs, off);
    vs = __shfl(vs, 0);
    float rstd = rsqrtf(vs * (1.0f / CC) + 1e-5f);
    xst[lane][wave]       = d0 * rstd * ln_g[lane]       + ln_b[lane];
    xst[lane + 64][wave]  = d1 * rstd * ln_g[lane + 64]  + ln_b[lane + 64];
    xst[lane + 128][wave] = d2 * rstd * ln_g[lane + 128] + ln_b[lane + 128];
    xst[lane + 192][wave] = d3 * rstd * ln_g[lane + 192] + ln_b[lane + 192];
    __syncthreads();
    float a0 = b_in[t], a1 = a0, a2 = a0, a3 = a0;
    #pragma unroll 8
    for (int k = 0; k < CC; ++k) {
        float4 xv = *(const float4*)xst[k];     // uniform addr -> broadcast
        float wv = W_in[k * CC + t];
        a0 = fmaf(xv.x, wv, a0); a1 = fmaf(xv.y, wv, a1);
        a2 = fmaf(xv.z, wv, a2); a3 = fmaf(xv.w, wv, a3);
    }
    float h0 = gelu_fast(a0), h1 = gelu_fast(a1);
    float h2 = gelu_fast(a2), h3 = gelu_fast(a3);
    float p0 = policy[row0], p1 = policy[row0 + 1];
    float p2 = policy[row0 + 2], p3 = policy[row0 + 3];
    if (t < HALF) {
        hst[t][0] = h0; hst[t][1] = h1; hst[t][2] = h2; hst[t][3] = h3;
    } else {
        gpart[(size_t)blk * HALF + (t - HALF)] =
            h0 * p0 + h1 * p1 + h2 * p2 + h3 * p3;
    }
    if (t == 0) ppart[blk] = p0 + p1 + p2 + p3;
    __syncthreads();
    float c0 = 0, c1 = 0, c2 = 0, c3 = 0;
    #pragma unroll 8
    for (int k = 0; k < HALF; ++k) {
        float4 hv = *(const float4*)hst[k];     // uniform addr -> broadcast
        float wv = W1[k * CC + t];
        c0 = fmaf(hv.x, wv, c0); c1 = fmaf(hv.y, wv, c1);
        c2 = fmaf(hv.z, wv, c2); c3 = fmaf(hv.w, wv, c3);
    }
    int b = row0 >> 10;
    int lr = row0 & (NN - 1);
    size_t tb = ((size_t)(b * 64 + (lr >> 4)) * 32 + (t >> 3)) * 128 + (t & 7);
    int r16 = lr & 15;
    At[tb + (r16 + 0) * 8] = c0;
    At[tb + (r16 + 1) * 8] = c1;
    At[tb + (r16 + 2) * 8] = c2;
    At[tb + (r16 + 3) * 8] = c3;
}

// ---- kB: 200 blocks. Each redundantly reduces gpart/ppart for its b (L2-hot),
//      then Qc[row] = Qcq[row] + b1 + glob@W1[128:256]  (r14-proven pattern). ----
__global__ __launch_bounds__(256) void kB_combine(
        const float* __restrict__ W1, const float* __restrict__ gpart,
        const float* __restrict__ ppart, const float* __restrict__ b1,
        const float* __restrict__ Qcq, float* __restrict__ Qc) {
    __shared__ float gl2[2][HALF];
    __shared__ float gls[HALF];
    __shared__ float pss;
    int blk = blockIdx.x, t = threadIdx.x;
    int b = blk / NQ;
    int c = t & 127, hh = t >> 7;
    {
        const float* gp = gpart + ((size_t)b * 256 + hh * 128) * HALF + c;
        float s = 0.f;
        #pragma unroll 16
        for (int ch = 0; ch < 128; ++ch) s += gp[(size_t)ch * HALF];
        gl2[hh][c] = s;
    }
    if (t < 64) {
        const float* pp = ppart + b * 256;
        float ps = pp[t] + pp[t + 64] + pp[t + 128] + pp[t + 192];
        for (int off = 32; off; off >>= 1) ps += __shfl_down(ps, off);
        if (t == 0) pss = ps;
    }
    __syncthreads();
    if (t < HALF) gls[t] = (gl2[0][t] + gl2[1][t]) / pss;
    __syncthreads();
    float g = b1[t] + Qcq[(size_t)blk * CC + t];
    #pragma unroll 8
    for (int k = 0; k < HALF; ++k)
        g = fmaf(gls[k], W1[(HALF + k) * CC + t], g);
    Qc[(size_t)blk * CC + t] = g;
}

// ---- k5: r14-proven structure, occupancy bound lifted 4 -> 6 waves/EU.
// Block M=64 x N=128; 4 waves, wave-tile 16x128 (acc 32 AGPR, arch VGPR ~40:
// 72 total < 85 budget at 6 waves/EU). z1 = gelu(At + Qc) in-register; W2
// per-32k chunk in frag-tiled dbuf LDS (conflict-free); 3200 blocks. ----
__global__ __launch_bounds__(256, 6) void k5_main(
        const float* __restrict__ At, const float* __restrict__ Qc,
        const short* __restrict__ W2T, const float* __restrict__ b2,
        const float* __restrict__ W3, const float* __restrict__ b3,
        float* __restrict__ out) {
    __shared__ short w2s[2][4096];   // 2 x 8 KB

    int t = threadIdx.x;
    int lane = t & 63, w = t >> 6;
    int col16 = lane & 15, quad = lane >> 4;
    int blk = blockIdx.x;                // 0..3199
    int jt = blk & 15;                   // 16 j-tiles of 64 rows
    int iq = (blk >> 4) % NQ;
    int b  = blk / (16 * NQ);
    const float* Abase = At + ((size_t)(b * 64 + jt * 4 + w) * 32) * 128 + col16 * 8;
    const float* Qrow = Qc + (size_t)(b * NQ + iq) * CC;
    const short* Wg = W2T + (size_t)((t >> 6) * 32 + ((t >> 4) & 3)) * 128
                      + (t & 15) * 8;

    f32x4 acc[8];
    #pragma unroll
    for (int ni = 0; ni < 8; ++ni) acc[ni] = (f32x4){0.f, 0.f, 0.f, 0.f};

    // prologue: chunk0 -> buf0; chunk1 -> regs; A/Q(kt=0) -> regs
    bf16x8 nx0 = *(const bf16x8*)(Wg);
    bf16x8 nx1 = *(const bf16x8*)(Wg + 16384);
    float4 a0 = *(const float4*)(Abase + quad * 128);
    float4 a1 = *(const float4*)(Abase + quad * 128 + 4);
    float4 q0 = *(const float4*)(Qrow + quad * 8);
    float4 q1 = *(const float4*)(Qrow + quad * 8 + 4);
    *(bf16x8*)&w2s[0][t * 8] = nx0;
    *(bf16x8*)&w2s[0][2048 + t * 8] = nx1;
    nx0 = *(const bf16x8*)(Wg + 512);
    nx1 = *(const bf16x8*)(Wg + 16384 + 512);
    __syncthreads();

    #pragma unroll
    for (int kt = 0; kt < 8; ++kt) {
        int buf = kt & 1;
        if (kt < 7) {
            *(bf16x8*)&w2s[1 - buf][t * 8] = nx0;
            *(bf16x8*)&w2s[1 - buf][2048 + t * 8] = nx1;
        }
        if (kt < 6) {
            nx0 = *(const bf16x8*)(Wg + (kt + 2) * 512);
            nx1 = *(const bf16x8*)(Wg + 16384 + (kt + 2) * 512);
        }
        union { bf16x8 v; __hip_bfloat162 h[4]; } fr;
        fr.h[0] = __float22bfloat162_rn(make_float2(gelu_fast(a0.x + q0.x),
                                                   gelu_fast(a0.y + q0.y)));
        fr.h[1] = __float22bfloat162_rn(make_float2(gelu_fast(a0.z + q0.z),
                                                   gelu_fast(a0.w + q0.w)));
        fr.h[2] = __float22bfloat162_rn(make_float2(gelu_fast(a1.x + q1.x),
                                                   gelu_fast(a1.y + q1.y)));
        fr.h[3] = __float22bfloat162_rn(make_float2(gelu_fast(a1.z + q1.z),
                                                   gelu_fast(a1.w + q1.w)));
        if (kt < 7) {
            const float* Ap = Abase + (size_t)((kt + 1) * 4 + quad) * 128;
            a0 = *(const float4*)(Ap);
            a1 = *(const float4*)(Ap + 4);
            q0 = *(const float4*)(Qrow + (kt + 1) * 32 + quad * 8);
            q1 = *(const float4*)(Qrow + (kt + 1) * 32 + quad * 8 + 4);
        }
        #pragma unroll
        for (int ni = 0; ni < 8; ++ni) {
            bf16x8 bv = *(const bf16x8*)&w2s[buf][(ni * 64 + lane) * 8];
            acc[ni] = __builtin_amdgcn_mfma_f32_16x16x32_bf16(fr.v, bv,
                                                              acc[ni], 0, 0, 0);
        }
        if (kt < 7) __syncthreads();
    }

    // epilogue: z2 = gelu(acc + b2); logits = z2@W3; reduce over col16; lsm
    float p0[4] = {0, 0, 0, 0}, p1[4] = {0, 0, 0, 0};
    #pragma unroll
    for (int ni = 0; ni < 8; ++ni) {
        int c = ni * 16 + col16;
        float bb = b2[c];
        float2 w3v = *(const float2*)(W3 + c * 2);
        #pragma unroll
        for (int r = 0; r < 4; ++r) {
            float z = gelu_fast(acc[ni][r] + bb);
            p0[r] = fmaf(z, w3v.x, p0[r]);
            p1[r] = fmaf(z, w3v.y, p1[r]);
        }
    }
    float b30 = b3[0], b31 = b3[1];
    #pragma unroll
    for (int r = 0; r < 4; ++r) {
        float s0 = p0[r], s1 = p1[r];
        #pragma unroll
        for (int off = 1; off < 16; off <<= 1) {
            s0 += __shfl_xor(s0, off);
            s1 += __shfl_xor(s1, off);
        }
        if (col16 == 0) {
            float z0 = s0 + b30, z1v = s1 + b31;
            float m = fmaxf(z0, z1v);
            float lse = m + __logf(__expf(z0 - m) + __expf(z1v - m));
            int j = jt * 64 + w * 16 + quad * 4 + r;
            *(float2*)(out + ((size_t)(b * NQ + iq) * NN + j) * 2) =
                make_float2(z0 - lse, z1v - lse);
        }
    }
}

extern "C" void kernel_launch(void* const* d_in, const int* in_sizes, int n_in,
                              void* d_out, int out_size, void* d_ws, size_t ws_size,
                              hipStream_t stream) {
    const float* x      = (const float*)d_in[0];
    const float* query  = (const float*)d_in[1];
    const float* policy = (const float*)d_in[2];
    const float* ln_g   = (const float*)d_in[3];
    const float* ln_b   = (const float*)d_in[4];
    const float* W_in   = (const float*)d_in[5];
    const float* b_in   = (const float*)d_in[6];
    const float* W1     = (const float*)d_in[7];
    const float* b1     = (const float*)d_in[8];
    const float* W2     = (const float*)d_in[9];
    const float* b2     = (const float*)d_in[10];
    const float* W3     = (const float*)d_in[11];
    const float* b3     = (const float*)d_in[12];
    float* out = (float*)d_out;

    float* ws    = (float*)d_ws;
    float* At    = ws;                 // 524288 fp32 (MFMA-A-frag tiled)
    float* Qcq   = ws + 524288;        // 200*256
    float* Qc    = ws + 575488;        // 200*256 (combined)
    float* gpart = ws + 626688;        // 512*128
    float* ppart = ws + 692224;        // 512
    short* W2T   = (short*)(ws + 692736);  // 128*256 bf16, MFMA-B-frag tiled

    kA_fused<<<744, 256, 0, stream>>>(x, ln_g, ln_b, W_in, b_in, policy,
                                      query, W1, W2, At, Qcq, gpart, ppart, W2T);
    kB_combine<<<BB * NQ, 256, 0, stream>>>(W1, gpart, ppart, b1, Qcq, Qc);
    k5_main<<<3200, 256, 0, stream>>>(At, Qc, W2T, b2, W3, b3, out);
}